// Round 7
// baseline (1419.054 us; speedup 1.0000x reference)
//
#include <hip/hip_runtime.h>
#include <stdint.h>

// Problem constants (B=2,S=2048 -> T=4096 tokens)
#define TTOK  4096
#define DDIM  2048
#define NEXP  16
#define HDIM  1024
#define HSDIM 4096
#define CAPR  18432   // 4096*4 + 16*128 padded capacity (128-aligned segments)

typedef __bf16 bf16x8 __attribute__((ext_vector_type(8)));
typedef __bf16 bf16x4 __attribute__((ext_vector_type(4)));
typedef float  f32x4  __attribute__((ext_vector_type(4)));

__device__ __forceinline__ unsigned short f2b(float f) {
  union { float f; unsigned int i; } v; v.f = f;
  unsigned int r = (v.i + 0x7fffu + ((v.i >> 16) & 1u)) >> 16;
  return (unsigned short)r;
}
__device__ __forceinline__ float b2f(unsigned short u) {
  union { unsigned int i; float f; } v; v.i = ((unsigned int)u) << 16; return v.f;
}
__device__ __forceinline__ float silu_f(float x) { return x / (1.f + __expf(-x)); }

// async global->LDS, 16B per lane. LDS dest must be wave-uniform (HW adds lane*16).
__device__ __forceinline__ void gload16(const void* g, void* l) {
  __builtin_amdgcn_global_load_lds(
      (const __attribute__((address_space(1))) unsigned int*)(uintptr_t)g,
      (__attribute__((address_space(3))) unsigned int*)(uintptr_t)l,
      16, 0, 0);
}

// bijective XCD-aware swizzle (m204 form), 1D grid
__device__ __forceinline__ int xcd_swz(int bid, int nwg) {
  int q = nwg >> 3, r = nwg & 7;
  int xcd = bid & 7, off = bid >> 3;
  return (xcd < r ? xcd * (q + 1) : r * (q + 1) + (xcd - r) * q) + off;
}

// supertile mapping: 4m x 8n supertiles, n-fastest inside.
// requires MB%4==0 && NB%8==0 (true for all launches here).
__device__ __forceinline__ void tile_map(int wg, int MB, int NB, int& mb, int& nb) {
  int st = wg >> 5;            // supertile index (32 wgs each)
  int in = wg & 31;
  int sm = MB >> 2;            // supertiles along m
  int stm = st % sm;
  int stn = st / sm;
  mb = stm * 4 + (in >> 3);
  nb = stn * 8 + (in & 7);
}

// ---------------------------------------------------------------------
// Fused transpose+cvt staging: fp32 k-major W tile [64 k][128 n] (global)
//   -> bf16 LDS tile [128 n-rows][64 k], XOR-swizzled (chunk ^= row&7).
// 512 threads: thread covers k in [kq,kq+4) x n in [nq,nq+4).
// Reads: 4 x float4, wave = 16 rows x 64B contiguous segments.
// Writes: 4 x ds_write_b64; wave64 x 8B = 512B = 4 bank-cycles (minimum).
// ---------------------------------------------------------------------
__device__ __forceinline__ void stage_w_f32(const float* __restrict__ Wsrc, int N,
                                            unsigned short* lds, int tid) {
  const int kq = (tid & 15) * 4;        // 0..60
  const int nq = (tid >> 4) * 4;        // 0..124
  const float* p = Wsrc + (size_t)kq * N + nq;
  float a[4][4] __attribute__((aligned(16)));
  *(float4*)a[0] = *(const float4*)p;
  *(float4*)a[1] = *(const float4*)(p + (size_t)N);
  *(float4*)a[2] = *(const float4*)(p + 2 * (size_t)N);
  *(float4*)a[3] = *(const float4*)(p + 3 * (size_t)N);
  const int kch = kq >> 3;              // logical 16B chunk along k
  const int ksub = (kq & 4) * 2;        // byte offset within chunk (0 or 8)
#pragma unroll
  for (int j = 0; j < 4; ++j) {
    int row = nq + j;
    int byte = row * 128 + ((kch ^ (row & 7)) << 4) + ksub;
    bf16x4 w = { (__bf16)a[0][j], (__bf16)a[1][j], (__bf16)a[2][j], (__bf16)a[3][j] };
    *(bf16x4*)((char*)lds + byte) = w;
  }
}

// ---------- fp32 -> bf16 bulk convert (8 elems/thread) ----------
__global__ void cvt_bf16_kernel(const float* __restrict__ in, unsigned short* __restrict__ out, int n8) {
  int i = blockIdx.x * 256 + threadIdx.x;
  if (i >= n8) return;
  const float4* p = (const float4*)in + (size_t)i * 2;
  float4 a = p[0], b = p[1];
  uint4 o;
  o.x = (unsigned)f2b(a.x) | ((unsigned)f2b(a.y) << 16);
  o.y = (unsigned)f2b(a.z) | ((unsigned)f2b(a.w) << 16);
  o.z = (unsigned)f2b(b.x) | ((unsigned)f2b(b.y) << 16);
  o.w = (unsigned)f2b(b.z) | ((unsigned)f2b(b.w) << 16);
  ((uint4*)out)[i] = o;
}

// ---------- router: logits, top-4 by logit, renormalized softmax weights ----------
__global__ __launch_bounds__(256) void router_kernel(const float* __restrict__ x, const float* __restrict__ wr,
                                                     float* __restrict__ topw, int* __restrict__ topi) {
  int tok = blockIdx.x * 4 + (threadIdx.x >> 6);
  int lane = threadIdx.x & 63;
  const float* xr = x + (size_t)tok * DDIM;
  float acc[NEXP];
#pragma unroll
  for (int e = 0; e < NEXP; ++e) acc[e] = 0.f;
  for (int it = 0; it < DDIM / 64; ++it) {
    int d = it * 64 + lane;
    float xv = xr[d];
    const float4* w4 = (const float4*)(wr + (size_t)d * NEXP);
    float4 w0 = w4[0], w1 = w4[1], w2 = w4[2], w3 = w4[3];
    acc[0] += xv * w0.x; acc[1] += xv * w0.y; acc[2] += xv * w0.z; acc[3] += xv * w0.w;
    acc[4] += xv * w1.x; acc[5] += xv * w1.y; acc[6] += xv * w1.z; acc[7] += xv * w1.w;
    acc[8] += xv * w2.x; acc[9] += xv * w2.y; acc[10] += xv * w2.z; acc[11] += xv * w2.w;
    acc[12] += xv * w3.x; acc[13] += xv * w3.y; acc[14] += xv * w3.z; acc[15] += xv * w3.w;
  }
#pragma unroll
  for (int e = 0; e < NEXP; ++e) {
#pragma unroll
    for (int off = 32; off > 0; off >>= 1) acc[e] += __shfl_xor(acc[e], off);
  }
  unsigned used = 0u;
  float lv[4]; int si[4];
#pragma unroll
  for (int k = 0; k < 4; ++k) {
    float best = -3.4e38f; int bi = 0;
    for (int e = 0; e < NEXP; ++e) {
      if (!((used >> e) & 1u) && acc[e] > best) { best = acc[e]; bi = e; }
    }
    used |= 1u << bi; lv[k] = best; si[k] = bi;
  }
  if (lane == 0) {
    float m = lv[0], s = 0.f, w[4];
#pragma unroll
    for (int k = 0; k < 4; ++k) { w[k] = __expf(lv[k] - m); s += w[k]; }
    float inv = 1.f / s;
#pragma unroll
    for (int k = 0; k < 4; ++k) { topw[tok * 4 + k] = w[k] * inv; topi[tok * 4 + k] = si[k]; }
  }
}

// ---------- tiny bookkeeping kernels ----------
__global__ void zero_kernel(int* b) { if (threadIdx.x < 64) b[threadIdx.x] = 0; }

__global__ void count_kernel(const int* __restrict__ topi, int* counts, int n) {
  int i = blockIdx.x * 256 + threadIdx.x;
  if (i < n) atomicAdd(&counts[topi[i]], 1);
}

__global__ void offsets_kernel(const int* counts, int* eoff) {
  if (threadIdx.x == 0 && blockIdx.x == 0) {
    int o = 0;
    for (int e = 0; e < NEXP; ++e) { eoff[e] = o; o += (counts[e] + 127) & ~127; }
    eoff[NEXP] = o;
  }
}

__global__ void prefill_kernel(int* gtok, float* gwt, int cap) {
  int i = blockIdx.x * 256 + threadIdx.x;
  if (i < cap) { gtok[i] = 0; gwt[i] = 0.f; }
}

__global__ void scatter_kernel(const int* __restrict__ topi, const float* __restrict__ topw,
                               const int* __restrict__ eoff, int* cursors,
                               int* gtok, float* gwt, int* posmap, int n) {
  int i = blockIdx.x * 256 + threadIdx.x;
  if (i >= n) return;
  int e = topi[i];
  int pos = eoff[e] + atomicAdd(&cursors[e], 1);
  gtok[pos] = i >> 2;
  gwt[pos] = topw[i] * 0.8f;   // fold k/(k+1)
  posmap[i] = pos;
}

// ---------- final combine: out = 0.2*shared (already in out) + sum_k ecout[pos[t][k]] ----------
__global__ __launch_bounds__(256) void combine_kernel(const unsigned short* __restrict__ ecout,
                                                      const int* __restrict__ posmap,
                                                      float* __restrict__ out, int n8) {
  int i = blockIdx.x * 256 + threadIdx.x;   // one thread per 8 d-elems
  if (i >= n8) return;
  int t = i >> 8;                            // DDIM/8 = 256 chunks per token
  int c = i & 255;
  int4 pv = *(const int4*)&posmap[t * 4];
  float s[8];
  float4 o0 = ((const float4*)out)[(size_t)i * 2];
  float4 o1 = ((const float4*)out)[(size_t)i * 2 + 1];
  s[0]=o0.x; s[1]=o0.y; s[2]=o0.z; s[3]=o0.w; s[4]=o1.x; s[5]=o1.y; s[6]=o1.z; s[7]=o1.w;
  int pos[4] = {pv.x, pv.y, pv.z, pv.w};
#pragma unroll
  for (int k = 0; k < 4; ++k) {
    uint4 v = ((const uint4*)(ecout + (size_t)pos[k] * DDIM))[c];
    unsigned* pw = (unsigned*)&v;
#pragma unroll
    for (int w = 0; w < 4; ++w) {
      s[w * 2]     += b2f((unsigned short)(pw[w] & 0xffffu));
      s[w * 2 + 1] += b2f((unsigned short)(pw[w] >> 16));
    }
  }
  float4 r0 = {s[0], s[1], s[2], s[3]}, r1 = {s[4], s[5], s[6], s[7]};
  ((float4*)out)[(size_t)i * 2] = r0;
  ((float4*)out)[(size_t)i * 2 + 1] = r1;
}

// =====================================================================
// Dual-B SwiGLU GEMM: G[M,N] = silu(A@W1) * (A@W3) * scale, 128x128 tile,
// BK=64, 512 thr / 8 waves (wave tile 64x32).
// W1,W3 are k-major fp32 [K][N] (original layout!) — transposed+converted
// on the fly into swizzled bf16 LDS by stage_w_f32.
// MODE 0: direct A rows, single weight pair, scale=1
// MODE 2: A rows gathered via gtok[], per-expert weights, scale=gwt[row]
// =====================================================================
template <int MODE>
__global__ __launch_bounds__(512) void gemm_dual(const unsigned short* __restrict__ A,
                                                 const float* __restrict__ W1,
                                                 const float* __restrict__ W3,
                                                 unsigned short* __restrict__ G,
                                                 int N, int K, int MB,
                                                 const int* __restrict__ gtok,
                                                 const float* __restrict__ gwt,
                                                 const int* __restrict__ eoff) {
  __shared__ unsigned short sA[128 * 64];
  __shared__ unsigned short s1[128 * 64];
  __shared__ unsigned short s3[128 * 64];
  __shared__ int sIdx[128];

  int nwg = gridDim.x;
  int wg = xcd_swz(blockIdx.x, nwg);
  int mb, nb;
  tile_map(wg, MB, nwg / MB, mb, nb);
  int m0 = mb * 128;
  int n0 = nb * 128;

  const float* W1e = W1;
  const float* W3e = W3;
  if constexpr (MODE == 2) {
    if (m0 >= eoff[NEXP]) return;              // block-uniform
    int e = 0;
    while (m0 >= eoff[e + 1]) ++e;
    size_t wofs = (size_t)e * N * K;
    W1e += wofs; W3e += wofs;
  }

  int tid = threadIdx.x, lane = tid & 63, wv = tid >> 6;
  if constexpr (MODE == 2) {
    if (tid < 128) sIdx[tid] = gtok[m0 + tid];
    __syncthreads();
  }

  int wm = wv >> 2, wn = wv & 3;             // wave tile: rows wm*64+, cols wn*32+
  f32x4 ac1[4][2], ac3[4][2];
#pragma unroll
  for (int mi = 0; mi < 4; ++mi)
#pragma unroll
    for (int ni = 0; ni < 2; ++ni) { ac1[mi][ni] = (f32x4){0,0,0,0}; ac3[mi][ni] = (f32x4){0,0,0,0}; }

  for (int kt = 0; kt < K; kt += 64) {
    // A: async DMA into swizzled LDS (issued first, overlaps W reg-staging)
#pragma unroll
    for (int c = 0; c < 2; ++c) {
      int bofs = (wv * 2 + c) * 1024 + lane * 16;          // byte offset within tile
      int row = bofs >> 7;                                 // 128 B per row
      int sch = ((bofs >> 4) & 7) ^ (row & 7);             // source chunk (inverse swizzle)
      int ar;
      if constexpr (MODE == 2) ar = sIdx[row]; else ar = m0 + row;
      gload16(A + (size_t)ar * K + kt + sch * 8, &sA[(wv * 2 + c) * 512]);
    }
    // W1, W3: fused transpose+cvt from fp32 k-major
    stage_w_f32(W1e + (size_t)kt * N + n0, N, s1, tid);
    stage_w_f32(W3e + (size_t)kt * N + n0, N, s3, tid);
    __syncthreads();
#pragma unroll
    for (int kk = 0; kk < 2; ++kk) {
      bf16x8 af[4], b1[2], b3[2];
#pragma unroll
      for (int mi = 0; mi < 4; ++mi) {
        int row = wm * 64 + mi * 16 + (lane & 15);
        int ch = (kk * 4 + (lane >> 4)) ^ (row & 7);
        af[mi] = *(const bf16x8*)&sA[row * 64 + ch * 8];
      }
#pragma unroll
      for (int ni = 0; ni < 2; ++ni) {
        int row = wn * 32 + ni * 16 + (lane & 15);
        int ch = (kk * 4 + (lane >> 4)) ^ (row & 7);
        b1[ni] = *(const bf16x8*)&s1[row * 64 + ch * 8];
        b3[ni] = *(const bf16x8*)&s3[row * 64 + ch * 8];
      }
#pragma unroll
      for (int mi = 0; mi < 4; ++mi)
#pragma unroll
        for (int ni = 0; ni < 2; ++ni) {
          ac1[mi][ni] = __builtin_amdgcn_mfma_f32_16x16x32_bf16(af[mi], b1[ni], ac1[mi][ni], 0, 0, 0);
          ac3[mi][ni] = __builtin_amdgcn_mfma_f32_16x16x32_bf16(af[mi], b3[ni], ac3[mi][ni], 0, 0, 0);
        }
    }
    __syncthreads();
  }

  // epilogue: g = silu(c1)*c3*scale ; C/D layout col=lane&15, row=(lane>>4)*4+j
#pragma unroll
  for (int mi = 0; mi < 4; ++mi)
#pragma unroll
    for (int ni = 0; ni < 2; ++ni) {
      int cc = n0 + wn * 32 + ni * 16 + (lane & 15);
#pragma unroll
      for (int j = 0; j < 4; ++j) {
        int rr = m0 + wm * 64 + mi * 16 + ((lane >> 4) << 2) + j;
        float sc;
        if constexpr (MODE == 2) sc = gwt[rr]; else sc = 1.f;
        float g = silu_f(ac1[mi][ni][j]) * ac3[mi][ni][j] * sc;
        G[(size_t)rr * N + cc] = f2b(g);
      }
    }
}

// ---------- single-B bf16 GEMM: 128x256 tile, BK=64, 512 thr / 8 waves ----------
// B is k-major fp32 [K][N] (original layout), staged via stage_w_f32 (2 halves).
// MODE 1: direct A, Cf = v*scale (fp32)
// MODE 4: direct A (gathered space), per-expert B segment, C->bf16
template <int MODE>
__global__ __launch_bounds__(512) void gemm_bt8(const unsigned short* __restrict__ A,
                                                const float* __restrict__ Bf,
                                                unsigned short* __restrict__ Cbf,
                                                float* __restrict__ Cf,
                                                int N, int K, int MB,
                                                const int* __restrict__ eoff,
                                                float scale) {
  __shared__ unsigned short sA[128 * 64];   // 16 KB
  __shared__ unsigned short sB[256 * 64];   // 32 KB

  int nwg = gridDim.x;
  int wg = xcd_swz(blockIdx.x, nwg);
  int mb, nb;
  tile_map(wg, MB, nwg / MB, mb, nb);
  int m0 = mb * 128;
  int n0 = nb * 256;

  const float* Bte = Bf;
  if constexpr (MODE == 4) {
    if (m0 >= eoff[NEXP]) return;
    int e = 0;
    while (m0 >= eoff[e + 1]) ++e;
    Bte = Bf + (size_t)e * N * K;
  }
  int tid = threadIdx.x, lane = tid & 63, wv = tid >> 6;
  int wm = wv >> 2, wn = wv & 3;            // wave tile: rows wm*64+, cols wn*64+
  f32x4 acc[4][4];
#pragma unroll
  for (int mi = 0; mi < 4; ++mi)
#pragma unroll
    for (int ni = 0; ni < 4; ++ni) acc[mi][ni] = (f32x4){0.f, 0.f, 0.f, 0.f};

  for (int kt = 0; kt < K; kt += 64) {
#pragma unroll
    for (int c = 0; c < 2; ++c) {           // stage A (16 KB, async DMA)
      int bofs = (wv * 2 + c) * 1024 + lane * 16;
      int row = bofs >> 7;
      int sch = ((bofs >> 4) & 7) ^ (row & 7);
      gload16(A + (size_t)(m0 + row) * K + kt + sch * 8, &sA[(wv * 2 + c) * 512]);
    }
    // stage B (256 n-rows, two 128-row halves) from fp32 k-major
    stage_w_f32(Bte + (size_t)kt * N + n0,       N, sB,            tid);
    stage_w_f32(Bte + (size_t)kt * N + n0 + 128, N, sB + 128 * 64, tid);
    __syncthreads();
#pragma unroll
    for (int kk = 0; kk < 2; ++kk) {
      bf16x8 af[4], bfv[4];
#pragma unroll
      for (int mi = 0; mi < 4; ++mi) {
        int row = wm * 64 + mi * 16 + (lane & 15);
        int ch = (kk * 4 + (lane >> 4)) ^ (row & 7);
        af[mi] = *(const bf16x8*)&sA[row * 64 + ch * 8];
      }
#pragma unroll
      for (int ni = 0; ni < 4; ++ni) {
        int row = wn * 64 + ni * 16 + (lane & 15);
        int ch = (kk * 4 + (lane >> 4)) ^ (row & 7);
        bfv[ni] = *(const bf16x8*)&sB[row * 64 + ch * 8];
      }
#pragma unroll
      for (int mi = 0; mi < 4; ++mi)
#pragma unroll
        for (int ni = 0; ni < 4; ++ni)
          acc[mi][ni] = __builtin_amdgcn_mfma_f32_16x16x32_bf16(af[mi], bfv[ni], acc[mi][ni], 0, 0, 0);
    }
    __syncthreads();
  }

#pragma unroll
  for (int mi = 0; mi < 4; ++mi)
#pragma unroll
    for (int ni = 0; ni < 4; ++ni) {
      int cc = n0 + wn * 64 + ni * 16 + (lane & 15);
#pragma unroll
      for (int j = 0; j < 4; ++j) {
        int rr = m0 + wm * 64 + mi * 16 + ((lane >> 4) << 2) + j;
        float v = acc[mi][ni][j];
        if constexpr (MODE == 1) Cf[(size_t)rr * N + cc] = v * scale;
        else Cbf[(size_t)rr * N + cc] = f2b(v);
      }
    }
}

extern "C" void kernel_launch(void* const* d_in, const int* in_sizes, int n_in,
                              void* d_out, int out_size, void* d_ws, size_t ws_size,
                              hipStream_t stream) {
  const float* x   = (const float*)d_in[0];
  const float* wr  = (const float*)d_in[1];
  const float* we1 = (const float*)d_in[2];
  const float* we3 = (const float*)d_in[3];
  const float* we2 = (const float*)d_in[4];
  const float* ws1 = (const float*)d_in[5];
  const float* ws3 = (const float*)d_in[6];
  const float* ws2 = (const float*)d_in[7];
  float* out = (float*)d_out;   // fp32 output per reference dtype

  char* p = (char*)d_ws;
  auto take = [&](size_t bytes) { char* r = p; p += (bytes + 255) & ~(size_t)255; return r; };
  unsigned short* xbf   = (unsigned short*)take((size_t)TTOK * DDIM * 2);    // 16 MiB
  unsigned short* ehg   = (unsigned short*)take((size_t)CAPR * HDIM * 2);    // 36 MiB (expert g)
  unsigned short* gsh   = (unsigned short*)take((size_t)TTOK * HSDIM * 2);   // 32 MiB (shared g)
  unsigned short* ecout = (unsigned short*)take((size_t)CAPR * DDIM * 2);    // 72 MiB
  float* topw = (float*)take((size_t)TTOK * 4 * 4);
  int*   topi = (int*)take((size_t)TTOK * 4 * 4);
  int*   gtok = (int*)take((size_t)CAPR * 4);
  float* gwt  = (float*)take((size_t)CAPR * 4);
  int*   posmap = (int*)take((size_t)TTOK * 4 * 4);
  int*   ibuf = (int*)take(256);   // [0:16) counts, [16:32) cursors, [32:49) eoff
  if ((size_t)(p - (char*)d_ws) > ws_size) return;  // ws too small -> visible failure

  int* counts  = ibuf;
  int* cursors = ibuf + 16;
  int* eoff    = ibuf + 32;

  // ---- prep: x -> bf16; router; permutation ----
  cvt_bf16_kernel<<<TTOK * DDIM / 8 / 256, 256, 0, stream>>>(x, xbf, TTOK * DDIM / 8);
  router_kernel<<<TTOK / 4, 256, 0, stream>>>(x, wr, topw, topi);
  zero_kernel<<<1, 64, 0, stream>>>(ibuf);
  count_kernel<<<TTOK * 4 / 256, 256, 0, stream>>>(topi, counts, TTOK * 4);
  offsets_kernel<<<1, 64, 0, stream>>>(counts, eoff);
  prefill_kernel<<<CAPR / 256, 256, 0, stream>>>(gtok, gwt, CAPR);
  scatter_kernel<<<TTOK * 4 / 256, 256, 0, stream>>>(topi, topw, eoff, cursors, gtok, gwt, posmap, TTOK * 4);

  // ---- shared MLP: gsh = silu(x@ws1)*(x@ws3); out = 0.2 * gsh @ ws2 ----
  gemm_dual<0><<<(TTOK / 128) * (HSDIM / 128), 512, 0, stream>>>(xbf, ws1, ws3, gsh, HSDIM, DDIM,
                                                                 TTOK / 128, nullptr, nullptr, nullptr);
  gemm_bt8<1><<<(TTOK / 128) * (DDIM / 256), 512, 0, stream>>>(gsh, ws2, nullptr, out, DDIM, HSDIM,
                                                               TTOK / 128, nullptr, 0.2f);

  // ---- experts (single merged launch over all 16): ehg = silu(xg@we1)*(xg@we3)*gwt ----
  gemm_dual<2><<<(CAPR / 128) * (HDIM / 128), 512, 0, stream>>>(xbf, we1, we3, ehg, HDIM, DDIM,
                                                                CAPR / 128, gtok, gwt, eoff);
  // expert GEMM2: ecout = ehg @ we2 (per-expert), bf16 at gathered rows
  gemm_bt8<4><<<(CAPR / 128) * (DDIM / 256), 512, 0, stream>>>(ehg, we2, ecout, nullptr, DDIM, HDIM,
                                                               CAPR / 128, eoff, 0.f);

  // ---- out = 0.2*shared + sum_k ecout[pos[t][k]] ----
  combine_kernel<<<TTOK * DDIM / 8 / 256, 256, 0, stream>>>(ecout, posmap, out, TTOK * DDIM / 8);
}

// Round 8
// 932.007 us; speedup vs baseline: 1.5226x; 1.5226x over previous
//
#include <hip/hip_runtime.h>
#include <stdint.h>

// Problem constants (B=2,S=2048 -> T=4096 tokens)
#define TTOK  4096
#define DDIM  2048
#define NEXP  16
#define HDIM  1024
#define HSDIM 4096
#define CAPR  18432   // 4096*4 + 16*128 padded capacity (128-aligned segments)

typedef __bf16 bf16x8 __attribute__((ext_vector_type(8)));
typedef float  f32x4  __attribute__((ext_vector_type(4)));

__device__ __forceinline__ unsigned short f2b(float f) {
  union { float f; unsigned int i; } v; v.f = f;
  unsigned int r = (v.i + 0x7fffu + ((v.i >> 16) & 1u)) >> 16;
  return (unsigned short)r;
}
__device__ __forceinline__ float b2f(unsigned short u) {
  union { unsigned int i; float f; } v; v.i = ((unsigned int)u) << 16; return v.f;
}
__device__ __forceinline__ float silu_f(float x) { return x / (1.f + __expf(-x)); }

// async global->LDS, 16B per lane. LDS dest must be wave-uniform (HW adds lane*16).
__device__ __forceinline__ void gload16(const void* g, void* l) {
  __builtin_amdgcn_global_load_lds(
      (const __attribute__((address_space(1))) unsigned int*)(uintptr_t)g,
      (__attribute__((address_space(3))) unsigned int*)(uintptr_t)l,
      16, 0, 0);
}

// bijective XCD-aware swizzle (m204 form), 1D grid
__device__ __forceinline__ int xcd_swz(int bid, int nwg) {
  int q = nwg >> 3, r = nwg & 7;
  int xcd = bid & 7, off = bid >> 3;
  return (xcd < r ? xcd * (q + 1) : r * (q + 1) + (xcd - r) * q) + off;
}

// supertile mapping: 4m x 8n supertiles, n-fastest inside.
// requires MB%4==0 && NB%8==0 (true for all launches here).
__device__ __forceinline__ void tile_map(int wg, int MB, int NB, int& mb, int& nb) {
  int st = wg >> 5;            // supertile index (32 wgs each)
  int in = wg & 31;
  int sm = MB >> 2;            // supertiles along m
  int stm = st % sm;
  int stn = st / sm;
  mb = stm * 4 + (in >> 3);
  nb = stn * 8 + (in & 7);
}

// ---------- fp32 -> bf16 bulk convert (8 elems/thread) ----------
__global__ void cvt_bf16_kernel(const float* __restrict__ in, unsigned short* __restrict__ out, int n8) {
  int i = blockIdx.x * 256 + threadIdx.x;
  if (i >= n8) return;
  const float4* p = (const float4*)in + (size_t)i * 2;
  float4 a = p[0], b = p[1];
  uint4 o;
  o.x = (unsigned)f2b(a.x) | ((unsigned)f2b(a.y) << 16);
  o.y = (unsigned)f2b(a.z) | ((unsigned)f2b(a.w) << 16);
  o.z = (unsigned)f2b(b.x) | ((unsigned)f2b(b.y) << 16);
  o.w = (unsigned)f2b(b.z) | ((unsigned)f2b(b.w) << 16);
  ((uint4*)out)[i] = o;
}

// ---------- transpose fp32 [R][C] -> bf16 [C][R], per blockIdx.z matrix ----------
// float4 global reads -> LDS; ushort8 (16B) packed global writes.
__global__ __launch_bounds__(256) void transpose_f2b(const float* __restrict__ in,
                                                     unsigned short* __restrict__ out, int R, int C) {
  __shared__ unsigned short t[64][68];
  size_t zo = (size_t)blockIdx.z * (size_t)R * C;
  int c0 = blockIdx.x * 64, r0 = blockIdx.y * 64;
  int tid = threadIdx.x;
#pragma unroll
  for (int p = 0; p < 4; ++p) {
    int id = p * 256 + tid;
    int r = id >> 4;               // 0..63
    int c4 = (id & 15) * 4;        // 0,4,..,60
    float4 v = *(const float4*)&in[zo + (size_t)(r0 + r) * C + c0 + c4];
    ushort4 w = { f2b(v.x), f2b(v.y), f2b(v.z), f2b(v.w) };
    *(ushort4*)&t[r][c4] = w;
  }
  __syncthreads();
#pragma unroll
  for (int p = 0; p < 2; ++p) {
    int id = p * 256 + tid;        // 0..511
    int c = id >> 3;               // 0..63
    int r8 = (id & 7) * 8;         // 0,8,..,56
    unsigned p0 = (unsigned)t[r8 + 0][c] | ((unsigned)t[r8 + 1][c] << 16);
    unsigned p1 = (unsigned)t[r8 + 2][c] | ((unsigned)t[r8 + 3][c] << 16);
    unsigned p2 = (unsigned)t[r8 + 4][c] | ((unsigned)t[r8 + 5][c] << 16);
    unsigned p3 = (unsigned)t[r8 + 6][c] | ((unsigned)t[r8 + 7][c] << 16);
    uint4 o = { p0, p1, p2, p3 };
    *(uint4*)&out[zo + (size_t)(c0 + c) * R + r0 + r8] = o;
  }
}

// ---------- router: logits, top-4 by logit, renormalized softmax weights + expert counts ----------
__global__ __launch_bounds__(256) void router_kernel(const float* __restrict__ x, const float* __restrict__ wr,
                                                     float* __restrict__ topw, int* __restrict__ topi,
                                                     int* __restrict__ counts) {
  int tok = blockIdx.x * 4 + (threadIdx.x >> 6);
  int lane = threadIdx.x & 63;
  const float* xr = x + (size_t)tok * DDIM;
  float acc[NEXP];
#pragma unroll
  for (int e = 0; e < NEXP; ++e) acc[e] = 0.f;
  for (int it = 0; it < DDIM / 64; ++it) {
    int d = it * 64 + lane;
    float xv = xr[d];
    const float4* w4 = (const float4*)(wr + (size_t)d * NEXP);
    float4 w0 = w4[0], w1 = w4[1], w2 = w4[2], w3 = w4[3];
    acc[0] += xv * w0.x; acc[1] += xv * w0.y; acc[2] += xv * w0.z; acc[3] += xv * w0.w;
    acc[4] += xv * w1.x; acc[5] += xv * w1.y; acc[6] += xv * w1.z; acc[7] += xv * w1.w;
    acc[8] += xv * w2.x; acc[9] += xv * w2.y; acc[10] += xv * w2.z; acc[11] += xv * w2.w;
    acc[12] += xv * w3.x; acc[13] += xv * w3.y; acc[14] += xv * w3.z; acc[15] += xv * w3.w;
  }
#pragma unroll
  for (int e = 0; e < NEXP; ++e) {
#pragma unroll
    for (int off = 32; off > 0; off >>= 1) acc[e] += __shfl_xor(acc[e], off);
  }
  unsigned used = 0u;
  float lv[4]; int si[4];
#pragma unroll
  for (int k = 0; k < 4; ++k) {
    float best = -3.4e38f; int bi = 0;
    for (int e = 0; e < NEXP; ++e) {
      if (!((used >> e) & 1u) && acc[e] > best) { best = acc[e]; bi = e; }
    }
    used |= 1u << bi; lv[k] = best; si[k] = bi;
  }
  if (lane == 0) {
    float m = lv[0], s = 0.f, w[4];
#pragma unroll
    for (int k = 0; k < 4; ++k) { w[k] = __expf(lv[k] - m); s += w[k]; }
    float inv = 1.f / s;
#pragma unroll
    for (int k = 0; k < 4; ++k) {
      topw[tok * 4 + k] = w[k] * inv;
      topi[tok * 4 + k] = si[k];
      atomicAdd(&counts[si[k]], 1);
    }
  }
}

// ---------- tiny bookkeeping kernels ----------
__global__ void zero_kernel(int* b) { if (threadIdx.x < 64) b[threadIdx.x] = 0; }

__global__ void offsets_kernel(const int* counts, int* eoff) {
  if (threadIdx.x == 0 && blockIdx.x == 0) {
    int o = 0;
    for (int e = 0; e < NEXP; ++e) { eoff[e] = o; o += (counts[e] + 127) & ~127; }
    eoff[NEXP] = o;
  }
}

__global__ void prefill_kernel(int* gtok, float* gwt, int cap) {
  int i = blockIdx.x * 256 + threadIdx.x;
  if (i < cap) { gtok[i] = 0; gwt[i] = 0.f; }
}

__global__ void scatter_kernel(const int* __restrict__ topi, const float* __restrict__ topw,
                               const int* __restrict__ eoff, int* cursors,
                               int* gtok, float* gwt, int* posmap, int n) {
  int i = blockIdx.x * 256 + threadIdx.x;
  if (i >= n) return;
  int e = topi[i];
  int pos = eoff[e] + atomicAdd(&cursors[e], 1);
  gtok[pos] = i >> 2;
  gwt[pos] = topw[i] * 0.8f;   // fold k/(k+1)
  posmap[i] = pos;
}

// ---------- final combine: out = 0.2*shared (already in out) + sum_k ecout[pos[t][k]] ----------
__global__ __launch_bounds__(256) void combine_kernel(const unsigned short* __restrict__ ecout,
                                                      const int* __restrict__ posmap,
                                                      float* __restrict__ out, int n8) {
  int i = blockIdx.x * 256 + threadIdx.x;   // one thread per 8 d-elems
  if (i >= n8) return;
  int t = i >> 8;                            // DDIM/8 = 256 chunks per token
  int c = i & 255;
  int4 pv = *(const int4*)&posmap[t * 4];
  float s[8];
  float4 o0 = ((const float4*)out)[(size_t)i * 2];
  float4 o1 = ((const float4*)out)[(size_t)i * 2 + 1];
  s[0]=o0.x; s[1]=o0.y; s[2]=o0.z; s[3]=o0.w; s[4]=o1.x; s[5]=o1.y; s[6]=o1.z; s[7]=o1.w;
  int pos[4] = {pv.x, pv.y, pv.z, pv.w};
#pragma unroll
  for (int k = 0; k < 4; ++k) {
    uint4 v = ((const uint4*)(ecout + (size_t)pos[k] * DDIM))[c];
    unsigned* pw = (unsigned*)&v;
#pragma unroll
    for (int w = 0; w < 4; ++w) {
      s[w * 2]     += b2f((unsigned short)(pw[w] & 0xffffu));
      s[w * 2 + 1] += b2f((unsigned short)(pw[w] >> 16));
    }
  }
  float4 r0 = {s[0], s[1], s[2], s[3]}, r1 = {s[4], s[5], s[6], s[7]};
  ((float4*)out)[(size_t)i * 2] = r0;
  ((float4*)out)[(size_t)i * 2 + 1] = r1;
}

// =====================================================================
// Dual-B SwiGLU GEMM: G[M,N] = silu(A@W1^T) * (A@W3^T) * scale, 128x128 tile,
// BK=64, 512 thr / 8 waves (wave tile 64x32). W1,W3 are [N][K] bf16.
// MODE 0: direct A rows, single weight pair, scale=1
// MODE 2: A rows gathered via gtok[], per-expert weights, scale=gwt[row]
// =====================================================================
template <int MODE>
__global__ __launch_bounds__(512) void gemm_dual(const unsigned short* __restrict__ A,
                                                 const unsigned short* __restrict__ W1,
                                                 const unsigned short* __restrict__ W3,
                                                 unsigned short* __restrict__ G,
                                                 int N, int K, int MB,
                                                 const int* __restrict__ gtok,
                                                 const float* __restrict__ gwt,
                                                 const int* __restrict__ eoff) {
  __shared__ unsigned short sA[128 * 64];
  __shared__ unsigned short s1[128 * 64];
  __shared__ unsigned short s3[128 * 64];
  __shared__ int sIdx[128];

  int nwg = gridDim.x;
  int wg = xcd_swz(blockIdx.x, nwg);
  int mb, nb;
  tile_map(wg, MB, nwg / MB, mb, nb);
  int m0 = mb * 128;
  int n0 = nb * 128;

  const unsigned short* W1e = W1;
  const unsigned short* W3e = W3;
  if constexpr (MODE == 2) {
    if (m0 >= eoff[NEXP]) return;              // block-uniform
    int e = 0;
    while (m0 >= eoff[e + 1]) ++e;
    size_t wofs = (size_t)e * N * K;
    W1e += wofs; W3e += wofs;
  }

  int tid = threadIdx.x, lane = tid & 63, wv = tid >> 6;
  if constexpr (MODE == 2) {
    if (tid < 128) sIdx[tid] = gtok[m0 + tid];
    __syncthreads();
  }

  int wm = wv >> 2, wn = wv & 3;             // wave tile: rows wm*64+, cols wn*32+
  f32x4 ac1[4][2], ac3[4][2];
#pragma unroll
  for (int mi = 0; mi < 4; ++mi)
#pragma unroll
    for (int ni = 0; ni < 2; ++ni) { ac1[mi][ni] = (f32x4){0,0,0,0}; ac3[mi][ni] = (f32x4){0,0,0,0}; }

  for (int kt = 0; kt < K; kt += 64) {
    // stage A, W1, W3 tiles: [128 rows][64 k] bf16, XOR-swizzled via pre-swizzled source
#pragma unroll
    for (int c = 0; c < 2; ++c) {
      int bofs = (wv * 2 + c) * 1024 + lane * 16;          // byte offset within tile
      int row = bofs >> 7;                                 // 128 B per row
      int sch = ((bofs >> 4) & 7) ^ (row & 7);             // source chunk (inverse swizzle)
      int ar;
      if constexpr (MODE == 2) ar = sIdx[row]; else ar = m0 + row;
      gload16(A   + (size_t)ar * K        + kt + sch * 8, &sA[(wv * 2 + c) * 512]);
      gload16(W1e + (size_t)(n0 + row) * K + kt + sch * 8, &s1[(wv * 2 + c) * 512]);
      gload16(W3e + (size_t)(n0 + row) * K + kt + sch * 8, &s3[(wv * 2 + c) * 512]);
    }
    __syncthreads();
#pragma unroll
    for (int kk = 0; kk < 2; ++kk) {
      bf16x8 af[4], b1[2], b3[2];
#pragma unroll
      for (int mi = 0; mi < 4; ++mi) {
        int row = wm * 64 + mi * 16 + (lane & 15);
        int ch = (kk * 4 + (lane >> 4)) ^ (row & 7);
        af[mi] = *(const bf16x8*)&sA[row * 64 + ch * 8];
      }
#pragma unroll
      for (int ni = 0; ni < 2; ++ni) {
        int row = wn * 32 + ni * 16 + (lane & 15);
        int ch = (kk * 4 + (lane >> 4)) ^ (row & 7);
        b1[ni] = *(const bf16x8*)&s1[row * 64 + ch * 8];
        b3[ni] = *(const bf16x8*)&s3[row * 64 + ch * 8];
      }
#pragma unroll
      for (int mi = 0; mi < 4; ++mi)
#pragma unroll
        for (int ni = 0; ni < 2; ++ni) {
          ac1[mi][ni] = __builtin_amdgcn_mfma_f32_16x16x32_bf16(af[mi], b1[ni], ac1[mi][ni], 0, 0, 0);
          ac3[mi][ni] = __builtin_amdgcn_mfma_f32_16x16x32_bf16(af[mi], b3[ni], ac3[mi][ni], 0, 0, 0);
        }
    }
    __syncthreads();
  }

  // epilogue: g = silu(c1)*c3*scale ; C/D layout col=lane&15, row=(lane>>4)*4+j
#pragma unroll
  for (int mi = 0; mi < 4; ++mi)
#pragma unroll
    for (int ni = 0; ni < 2; ++ni) {
      int cc = n0 + wn * 32 + ni * 16 + (lane & 15);
#pragma unroll
      for (int j = 0; j < 4; ++j) {
        int rr = m0 + wm * 64 + mi * 16 + ((lane >> 4) << 2) + j;
        float sc;
        if constexpr (MODE == 2) sc = gwt[rr]; else sc = 1.f;
        float g = silu_f(ac1[mi][ni][j]) * ac3[mi][ni][j] * sc;
        G[(size_t)rr * N + cc] = f2b(g);
      }
    }
}

// ---------- single-B bf16 GEMM: 128x256 tile, BK=64, 512 thr / 8 waves ----------
// wave tile 64x64; MODE 1: direct A, Cf = v*scale (fp32)
// MODE 4: direct A (gathered space), per-expert Bt segment, C->bf16
template <int MODE>
__global__ __launch_bounds__(512) void gemm_bt8(const unsigned short* __restrict__ A,
                                                const unsigned short* __restrict__ Bt,
                                                unsigned short* __restrict__ Cbf,
                                                float* __restrict__ Cf,
                                                int N, int K, int MB,
                                                const int* __restrict__ eoff,
                                                float scale) {
  __shared__ unsigned short sA[128 * 64];   // 16 KB
  __shared__ unsigned short sB[256 * 64];   // 32 KB

  int nwg = gridDim.x;
  int wg = xcd_swz(blockIdx.x, nwg);
  int mb, nb;
  tile_map(wg, MB, nwg / MB, mb, nb);
  int m0 = mb * 128;
  int n0 = nb * 256;

  const unsigned short* Bte = Bt;
  if constexpr (MODE == 4) {
    if (m0 >= eoff[NEXP]) return;
    int e = 0;
    while (m0 >= eoff[e + 1]) ++e;
    Bte = Bt + (size_t)e * N * K;
  }
  int tid = threadIdx.x, lane = tid & 63, wv = tid >> 6;
  int wm = wv >> 2, wn = wv & 3;            // wave tile: rows wm*64+, cols wn*64+
  f32x4 acc[4][4];
#pragma unroll
  for (int mi = 0; mi < 4; ++mi)
#pragma unroll
    for (int ni = 0; ni < 4; ++ni) acc[mi][ni] = (f32x4){0.f, 0.f, 0.f, 0.f};

  for (int kt = 0; kt < K; kt += 64) {
#pragma unroll
    for (int c = 0; c < 2; ++c) {           // stage A (16 KB)
      int bofs = (wv * 2 + c) * 1024 + lane * 16;
      int row = bofs >> 7;
      int sch = ((bofs >> 4) & 7) ^ (row & 7);
      gload16(A + (size_t)(m0 + row) * K + kt + sch * 8, &sA[(wv * 2 + c) * 512]);
    }
#pragma unroll
    for (int c = 0; c < 4; ++c) {           // stage B (32 KB, 256 rows)
      int bofs = (wv * 4 + c) * 1024 + lane * 16;
      int row = bofs >> 7;
      int sch = ((bofs >> 4) & 7) ^ (row & 7);
      gload16(Bte + (size_t)(n0 + row) * K + kt + sch * 8, &sB[(wv * 4 + c) * 512]);
    }
    __syncthreads();
#pragma unroll
    for (int kk = 0; kk < 2; ++kk) {
      bf16x8 af[4], bfv[4];
#pragma unroll
      for (int mi = 0; mi < 4; ++mi) {
        int row = wm * 64 + mi * 16 + (lane & 15);
        int ch = (kk * 4 + (lane >> 4)) ^ (row & 7);
        af[mi] = *(const bf16x8*)&sA[row * 64 + ch * 8];
      }
#pragma unroll
      for (int ni = 0; ni < 4; ++ni) {
        int row = wn * 64 + ni * 16 + (lane & 15);
        int ch = (kk * 4 + (lane >> 4)) ^ (row & 7);
        bfv[ni] = *(const bf16x8*)&sB[row * 64 + ch * 8];
      }
#pragma unroll
      for (int mi = 0; mi < 4; ++mi)
#pragma unroll
        for (int ni = 0; ni < 4; ++ni)
          acc[mi][ni] = __builtin_amdgcn_mfma_f32_16x16x32_bf16(af[mi], bfv[ni], acc[mi][ni], 0, 0, 0);
    }
    __syncthreads();
  }

#pragma unroll
  for (int mi = 0; mi < 4; ++mi)
#pragma unroll
    for (int ni = 0; ni < 4; ++ni) {
      int cc = n0 + wn * 64 + ni * 16 + (lane & 15);
#pragma unroll
      for (int j = 0; j < 4; ++j) {
        int rr = m0 + wm * 64 + mi * 16 + ((lane >> 4) << 2) + j;
        float v = acc[mi][ni][j];
        if constexpr (MODE == 1) Cf[(size_t)rr * N + cc] = v * scale;
        else Cbf[(size_t)rr * N + cc] = f2b(v);
      }
    }
}

extern "C" void kernel_launch(void* const* d_in, const int* in_sizes, int n_in,
                              void* d_out, int out_size, void* d_ws, size_t ws_size,
                              hipStream_t stream) {
  const float* x   = (const float*)d_in[0];
  const float* wr  = (const float*)d_in[1];
  const float* we1 = (const float*)d_in[2];
  const float* we3 = (const float*)d_in[3];
  const float* we2 = (const float*)d_in[4];
  const float* ws1 = (const float*)d_in[5];
  const float* ws3 = (const float*)d_in[6];
  const float* ws2 = (const float*)d_in[7];
  float* out = (float*)d_out;   // fp32 output per reference dtype

  char* p = (char*)d_ws;
  auto take = [&](size_t bytes) { char* r = p; p += (bytes + 255) & ~(size_t)255; return r; };
  unsigned short* xbf   = (unsigned short*)take((size_t)TTOK * DDIM * 2);    // 16 MiB
  unsigned short* ehg   = (unsigned short*)take((size_t)CAPR * HDIM * 2);    // 36 MiB (expert g)
  unsigned short* gsh   = (unsigned short*)take((size_t)TTOK * HSDIM * 2);   // 32 MiB (shared g)
  unsigned short* ecout = (unsigned short*)take((size_t)CAPR * DDIM * 2);    // 72 MiB
  unsigned short* twArena = (unsigned short*)take((size_t)NEXP * HDIM * DDIM * 2);  // 64 MiB
  float* topw = (float*)take((size_t)TTOK * 4 * 4);
  int*   topi = (int*)take((size_t)TTOK * 4 * 4);
  int*   gtok = (int*)take((size_t)CAPR * 4);
  float* gwt  = (float*)take((size_t)CAPR * 4);
  int*   posmap = (int*)take((size_t)TTOK * 4 * 4);
  int*   ibuf = (int*)take(256);   // [0:16) counts, [16:32) cursors, [32:49) eoff
  if ((size_t)(p - (char*)d_ws) > ws_size) return;  // ws too small -> visible failure

  unsigned short* twA = twArena;                                   // first 32 MiB
  unsigned short* twB = twArena + (size_t)8 * DDIM * HDIM;         // second 32 MiB
  // we3^T (64 MiB) aliases gsh(32) + first 32 MiB of ecout — both dead in expert GEMM1 phase;
  // ecout's overlap region is rewritten only by gemm_bt8<4> afterwards.
  unsigned short* we3t = gsh;

  int* counts  = ibuf;
  int* cursors = ibuf + 16;
  int* eoff    = ibuf + 32;

  // ---- prep: x -> bf16; router (+counts); permutation ----
  zero_kernel<<<1, 64, 0, stream>>>(ibuf);
  cvt_bf16_kernel<<<TTOK * DDIM / 8 / 256, 256, 0, stream>>>(x, xbf, TTOK * DDIM / 8);
  router_kernel<<<TTOK / 4, 256, 0, stream>>>(x, wr, topw, topi, counts);
  offsets_kernel<<<1, 64, 0, stream>>>(counts, eoff);
  prefill_kernel<<<CAPR / 256, 256, 0, stream>>>(gtok, gwt, CAPR);
  scatter_kernel<<<TTOK * 4 / 256, 256, 0, stream>>>(topi, topw, eoff, cursors, gtok, gwt, posmap, TTOK * 4);

  // ---- shared MLP: gsh = silu(x@ws1)*(x@ws3); out = 0.2 * gsh @ ws2 ----
  transpose_f2b<<<dim3(HSDIM / 64, DDIM / 64, 1), 256, 0, stream>>>(ws1, twA, DDIM, HSDIM);
  transpose_f2b<<<dim3(HSDIM / 64, DDIM / 64, 1), 256, 0, stream>>>(ws3, twB, DDIM, HSDIM);
  gemm_dual<0><<<(TTOK / 128) * (HSDIM / 128), 512, 0, stream>>>(xbf, twA, twB, gsh, HSDIM, DDIM,
                                                                 TTOK / 128, nullptr, nullptr, nullptr);
  transpose_f2b<<<dim3(DDIM / 64, HSDIM / 64, 1), 256, 0, stream>>>(ws2, twA, HSDIM, DDIM);
  gemm_bt8<1><<<(TTOK / 128) * (DDIM / 256), 512, 0, stream>>>(gsh, twA, nullptr, out, DDIM, HSDIM,
                                                               TTOK / 128, nullptr, 0.2f);

  // ---- experts (single merged launch over all 16): ehg = silu(xg@we1)*(xg@we3)*gwt ----
  transpose_f2b<<<dim3(HDIM / 64, DDIM / 64, NEXP), 256, 0, stream>>>(we1, twArena, DDIM, HDIM);
  transpose_f2b<<<dim3(HDIM / 64, DDIM / 64, NEXP), 256, 0, stream>>>(we3, we3t, DDIM, HDIM);
  gemm_dual<2><<<(CAPR / 128) * (HDIM / 128), 512, 0, stream>>>(xbf, twArena, we3t, ehg, HDIM, DDIM,
                                                                CAPR / 128, gtok, gwt, eoff);
  // expert GEMM2: ecout = ehg @ we2 (per-expert), bf16 at gathered rows
  transpose_f2b<<<dim3(DDIM / 64, HDIM / 64, NEXP), 256, 0, stream>>>(we2, twArena, HDIM, DDIM);
  gemm_bt8<4><<<(CAPR / 128) * (DDIM / 256), 512, 0, stream>>>(ehg, twArena, ecout, nullptr, DDIM, HDIM,
                                                               CAPR / 128, eoff, 0.f);

  // ---- out = 0.2*shared + sum_k ecout[pos[t][k]] ----
  combine_kernel<<<TTOK * DDIM / 8 / 256, 256, 0, stream>>>(ecout, posmap, out, TTOK * DDIM / 8);
}

// Round 9
// 817.250 us; speedup vs baseline: 1.7364x; 1.1404x over previous
//
#include <hip/hip_runtime.h>
#include <stdint.h>

// Problem constants (B=2,S=2048 -> T=4096 tokens)
#define TTOK  4096
#define DDIM  2048
#define NEXP  16
#define HDIM  1024
#define HSDIM 4096
#define CAPR  18432   // 4096*4 + 16*128 padded capacity (128-aligned segments)

typedef __bf16 bf16x8 __attribute__((ext_vector_type(8)));
typedef float  f32x4  __attribute__((ext_vector_type(4)));

__device__ __forceinline__ unsigned short f2b(float f) {
  union { float f; unsigned int i; } v; v.f = f;
  unsigned int r = (v.i + 0x7fffu + ((v.i >> 16) & 1u)) >> 16;
  return (unsigned short)r;
}
__device__ __forceinline__ float b2f(unsigned short u) {
  union { unsigned int i; float f; } v; v.i = ((unsigned int)u) << 16; return v.f;
}
__device__ __forceinline__ float silu_f(float x) { return x / (1.f + __expf(-x)); }

// async global->LDS, 16B per lane. LDS dest must be wave-uniform (HW adds lane*16).
__device__ __forceinline__ void gload16(const void* g, void* l) {
  __builtin_amdgcn_global_load_lds(
      (const __attribute__((address_space(1))) unsigned int*)(uintptr_t)g,
      (__attribute__((address_space(3))) unsigned int*)(uintptr_t)l,
      16, 0, 0);
}

// bijective XCD-aware swizzle (m204 form), 1D grid
__device__ __forceinline__ int xcd_swz(int bid, int nwg) {
  int q = nwg >> 3, r = nwg & 7;
  int xcd = bid & 7, off = bid >> 3;
  return (xcd < r ? xcd * (q + 1) : r * (q + 1) + (xcd - r) * q) + off;
}

// supertile mapping: 4m x 8n supertiles, n-fastest inside.
// requires MB%4==0 && NB%8==0 (true for all launches here).
__device__ __forceinline__ void tile_map(int wg, int MB, int NB, int& mb, int& nb) {
  int st = wg >> 5;            // supertile index (32 wgs each)
  int in = wg & 31;
  int sm = MB >> 2;            // supertiles along m
  int stm = st % sm;
  int stn = st / sm;
  mb = stm * 4 + (in >> 3);
  nb = stn * 8 + (in & 7);
}

// ---------- fp32 -> bf16 bulk convert (8 elems/thread) ----------
__global__ void cvt_bf16_kernel(const float* __restrict__ in, unsigned short* __restrict__ out, int n8) {
  int i = blockIdx.x * 256 + threadIdx.x;
  if (i >= n8) return;
  const float4* p = (const float4*)in + (size_t)i * 2;
  float4 a = p[0], b = p[1];
  uint4 o;
  o.x = (unsigned)f2b(a.x) | ((unsigned)f2b(a.y) << 16);
  o.y = (unsigned)f2b(a.z) | ((unsigned)f2b(a.w) << 16);
  o.z = (unsigned)f2b(b.x) | ((unsigned)f2b(b.y) << 16);
  o.w = (unsigned)f2b(b.z) | ((unsigned)f2b(b.w) << 16);
  ((uint4*)out)[i] = o;
}

// ---------- transpose fp32 [R][C] -> bf16 [C][R], per blockIdx.z matrix ----------
// float4 global reads -> LDS; ushort8 (16B) packed global writes.
__global__ __launch_bounds__(256) void transpose_f2b(const float* __restrict__ in,
                                                     unsigned short* __restrict__ out, int R, int C) {
  __shared__ unsigned short t[64][68];
  size_t zo = (size_t)blockIdx.z * (size_t)R * C;
  int c0 = blockIdx.x * 64, r0 = blockIdx.y * 64;
  int tid = threadIdx.x;
#pragma unroll
  for (int p = 0; p < 4; ++p) {
    int id = p * 256 + tid;
    int r = id >> 4;               // 0..63
    int c4 = (id & 15) * 4;        // 0,4,..,60
    float4 v = *(const float4*)&in[zo + (size_t)(r0 + r) * C + c0 + c4];
    ushort4 w = { f2b(v.x), f2b(v.y), f2b(v.z), f2b(v.w) };
    *(ushort4*)&t[r][c4] = w;
  }
  __syncthreads();
#pragma unroll
  for (int p = 0; p < 2; ++p) {
    int id = p * 256 + tid;        // 0..511
    int c = id >> 3;               // 0..63
    int r8 = (id & 7) * 8;         // 0,8,..,56
    unsigned p0 = (unsigned)t[r8 + 0][c] | ((unsigned)t[r8 + 1][c] << 16);
    unsigned p1 = (unsigned)t[r8 + 2][c] | ((unsigned)t[r8 + 3][c] << 16);
    unsigned p2 = (unsigned)t[r8 + 4][c] | ((unsigned)t[r8 + 5][c] << 16);
    unsigned p3 = (unsigned)t[r8 + 6][c] | ((unsigned)t[r8 + 7][c] << 16);
    uint4 o = { p0, p1, p2, p3 };
    *(uint4*)&out[zo + (size_t)(c0 + c) * R + r0 + r8] = o;
  }
}

// ---------- router: logits, top-4 by logit, renormalized softmax weights ----------
// float4 loads, fully unrolled (8 iters) for ILP; latency-bound otherwise.
__global__ __launch_bounds__(256) void router_kernel(const float* __restrict__ x, const float* __restrict__ wr,
                                                     float* __restrict__ topw, int* __restrict__ topi) {
  int tok = blockIdx.x * 4 + (threadIdx.x >> 6);
  int lane = threadIdx.x & 63;
  const float4* xr = (const float4*)(x + (size_t)tok * DDIM);
  const float4* w4 = (const float4*)wr;
  float acc[NEXP];
#pragma unroll
  for (int e = 0; e < NEXP; ++e) acc[e] = 0.f;
#pragma unroll
  for (int it = 0; it < 8; ++it) {
    int d4 = it * 64 + lane;             // float4 index along d; rows d4*4 .. d4*4+3
    float4 xv = xr[d4];
#pragma unroll
    for (int r = 0; r < 4; ++r) {
      float xs = (r == 0) ? xv.x : (r == 1) ? xv.y : (r == 2) ? xv.z : xv.w;
      float4 w0 = w4[d4 * 16 + r * 4 + 0];
      float4 w1 = w4[d4 * 16 + r * 4 + 1];
      float4 w2 = w4[d4 * 16 + r * 4 + 2];
      float4 w3 = w4[d4 * 16 + r * 4 + 3];
      acc[0] += xs * w0.x; acc[1] += xs * w0.y; acc[2] += xs * w0.z; acc[3] += xs * w0.w;
      acc[4] += xs * w1.x; acc[5] += xs * w1.y; acc[6] += xs * w1.z; acc[7] += xs * w1.w;
      acc[8] += xs * w2.x; acc[9] += xs * w2.y; acc[10] += xs * w2.z; acc[11] += xs * w2.w;
      acc[12] += xs * w3.x; acc[13] += xs * w3.y; acc[14] += xs * w3.z; acc[15] += xs * w3.w;
    }
  }
#pragma unroll
  for (int e = 0; e < NEXP; ++e) {
#pragma unroll
    for (int off = 32; off > 0; off >>= 1) acc[e] += __shfl_xor(acc[e], off);
  }
  unsigned used = 0u;
  float lv[4]; int si[4];
#pragma unroll
  for (int k = 0; k < 4; ++k) {
    float best = -3.4e38f; int bi = 0;
    for (int e = 0; e < NEXP; ++e) {
      if (!((used >> e) & 1u) && acc[e] > best) { best = acc[e]; bi = e; }
    }
    used |= 1u << bi; lv[k] = best; si[k] = bi;
  }
  if (lane == 0) {
    float m = lv[0], s = 0.f, w[4];
#pragma unroll
    for (int k = 0; k < 4; ++k) { w[k] = __expf(lv[k] - m); s += w[k]; }
    float inv = 1.f / s;
#pragma unroll
    for (int k = 0; k < 4; ++k) { topw[tok * 4 + k] = w[k] * inv; topi[tok * 4 + k] = si[k]; }
  }
}

// ---------- tiny bookkeeping kernels ----------
__global__ void zero_kernel(int* b) { if (threadIdx.x < 64) b[threadIdx.x] = 0; }

__global__ void count_kernel(const int* __restrict__ topi, int* counts, int n) {
  int i = blockIdx.x * 256 + threadIdx.x;
  if (i < n) atomicAdd(&counts[topi[i]], 1);
}

__global__ void offsets_kernel(const int* counts, int* eoff) {
  if (threadIdx.x == 0 && blockIdx.x == 0) {
    int o = 0;
    for (int e = 0; e < NEXP; ++e) { eoff[e] = o; o += (counts[e] + 127) & ~127; }
    eoff[NEXP] = o;
  }
}

__global__ void prefill_kernel(int* gtok, float* gwt, int cap) {
  int i = blockIdx.x * 256 + threadIdx.x;
  if (i < cap) { gtok[i] = 0; gwt[i] = 0.f; }
}

__global__ void scatter_kernel(const int* __restrict__ topi, const float* __restrict__ topw,
                               const int* __restrict__ eoff, int* cursors,
                               int* gtok, float* gwt, int* posmap, int n) {
  int i = blockIdx.x * 256 + threadIdx.x;
  if (i >= n) return;
  int e = topi[i];
  int pos = eoff[e] + atomicAdd(&cursors[e], 1);
  gtok[pos] = i >> 2;
  gwt[pos] = topw[i] * 0.8f;   // fold k/(k+1)
  posmap[i] = pos;
}

// ---------- final combine: out = 0.2*shared (already in out) + sum_k ecout[pos[t][k]] ----------
__global__ __launch_bounds__(256) void combine_kernel(const unsigned short* __restrict__ ecout,
                                                      const int* __restrict__ posmap,
                                                      float* __restrict__ out, int n8) {
  int i = blockIdx.x * 256 + threadIdx.x;   // one thread per 8 d-elems
  if (i >= n8) return;
  int t = i >> 8;                            // DDIM/8 = 256 chunks per token
  int c = i & 255;
  int4 pv = *(const int4*)&posmap[t * 4];
  float s[8];
  float4 o0 = ((const float4*)out)[(size_t)i * 2];
  float4 o1 = ((const float4*)out)[(size_t)i * 2 + 1];
  s[0]=o0.x; s[1]=o0.y; s[2]=o0.z; s[3]=o0.w; s[4]=o1.x; s[5]=o1.y; s[6]=o1.z; s[7]=o1.w;
  int pos[4] = {pv.x, pv.y, pv.z, pv.w};
#pragma unroll
  for (int k = 0; k < 4; ++k) {
    uint4 v = ((const uint4*)(ecout + (size_t)pos[k] * DDIM))[c];
    unsigned* pw = (unsigned*)&v;
#pragma unroll
    for (int w = 0; w < 4; ++w) {
      s[w * 2]     += b2f((unsigned short)(pw[w] & 0xffffu));
      s[w * 2 + 1] += b2f((unsigned short)(pw[w] >> 16));
    }
  }
  float4 r0 = {s[0], s[1], s[2], s[3]}, r1 = {s[4], s[5], s[6], s[7]};
  ((float4*)out)[(size_t)i * 2] = r0;
  ((float4*)out)[(size_t)i * 2 + 1] = r1;
}

// =====================================================================
// Dual-B SwiGLU GEMM: G[M,N] = silu(A@W1^T) * (A@W3^T) * scale, 128x128 tile,
// BK=64, 512 thr / 8 waves (wave tile 64x32). W1,W3 are [N][K] bf16.
// MODE 0: direct A rows, single weight pair, scale=1
// MODE 2: A rows gathered via gtok[], per-expert weights, scale=gwt[row]
// =====================================================================
template <int MODE>
__global__ __launch_bounds__(512) void gemm_dual(const unsigned short* __restrict__ A,
                                                 const unsigned short* __restrict__ W1,
                                                 const unsigned short* __restrict__ W3,
                                                 unsigned short* __restrict__ G,
                                                 int N, int K, int MB,
                                                 const int* __restrict__ gtok,
                                                 const float* __restrict__ gwt,
                                                 const int* __restrict__ eoff) {
  __shared__ unsigned short sA[128 * 64];
  __shared__ unsigned short s1[128 * 64];
  __shared__ unsigned short s3[128 * 64];
  __shared__ int sIdx[128];

  int nwg = gridDim.x;
  int wg = xcd_swz(blockIdx.x, nwg);
  int mb, nb;
  tile_map(wg, MB, nwg / MB, mb, nb);
  int m0 = mb * 128;
  int n0 = nb * 128;

  const unsigned short* W1e = W1;
  const unsigned short* W3e = W3;
  if constexpr (MODE == 2) {
    if (m0 >= eoff[NEXP]) return;              // block-uniform
    int e = 0;
    while (m0 >= eoff[e + 1]) ++e;
    size_t wofs = (size_t)e * N * K;
    W1e += wofs; W3e += wofs;
  }

  int tid = threadIdx.x, lane = tid & 63, wv = tid >> 6;
  if constexpr (MODE == 2) {
    if (tid < 128) sIdx[tid] = gtok[m0 + tid];
    __syncthreads();
  }

  int wm = wv >> 2, wn = wv & 3;             // wave tile: rows wm*64+, cols wn*32+
  f32x4 ac1[4][2], ac3[4][2];
#pragma unroll
  for (int mi = 0; mi < 4; ++mi)
#pragma unroll
    for (int ni = 0; ni < 2; ++ni) { ac1[mi][ni] = (f32x4){0,0,0,0}; ac3[mi][ni] = (f32x4){0,0,0,0}; }

  for (int kt = 0; kt < K; kt += 64) {
    // stage A, W1, W3 tiles: [128 rows][64 k] bf16, XOR-swizzled via pre-swizzled source
#pragma unroll
    for (int c = 0; c < 2; ++c) {
      int bofs = (wv * 2 + c) * 1024 + lane * 16;          // byte offset within tile
      int row = bofs >> 7;                                 // 128 B per row
      int sch = ((bofs >> 4) & 7) ^ (row & 7);             // source chunk (inverse swizzle)
      int ar;
      if constexpr (MODE == 2) ar = sIdx[row]; else ar = m0 + row;
      gload16(A   + (size_t)ar * K        + kt + sch * 8, &sA[(wv * 2 + c) * 512]);
      gload16(W1e + (size_t)(n0 + row) * K + kt + sch * 8, &s1[(wv * 2 + c) * 512]);
      gload16(W3e + (size_t)(n0 + row) * K + kt + sch * 8, &s3[(wv * 2 + c) * 512]);
    }
    __syncthreads();
#pragma unroll
    for (int kk = 0; kk < 2; ++kk) {
      bf16x8 af[4], b1[2], b3[2];
#pragma unroll
      for (int mi = 0; mi < 4; ++mi) {
        int row = wm * 64 + mi * 16 + (lane & 15);
        int ch = (kk * 4 + (lane >> 4)) ^ (row & 7);
        af[mi] = *(const bf16x8*)&sA[row * 64 + ch * 8];
      }
#pragma unroll
      for (int ni = 0; ni < 2; ++ni) {
        int row = wn * 32 + ni * 16 + (lane & 15);
        int ch = (kk * 4 + (lane >> 4)) ^ (row & 7);
        b1[ni] = *(const bf16x8*)&s1[row * 64 + ch * 8];
        b3[ni] = *(const bf16x8*)&s3[row * 64 + ch * 8];
      }
#pragma unroll
      for (int mi = 0; mi < 4; ++mi)
#pragma unroll
        for (int ni = 0; ni < 2; ++ni) {
          ac1[mi][ni] = __builtin_amdgcn_mfma_f32_16x16x32_bf16(af[mi], b1[ni], ac1[mi][ni], 0, 0, 0);
          ac3[mi][ni] = __builtin_amdgcn_mfma_f32_16x16x32_bf16(af[mi], b3[ni], ac3[mi][ni], 0, 0, 0);
        }
    }
    __syncthreads();
  }

  // epilogue: g = silu(c1)*c3*scale ; C/D layout col=lane&15, row=(lane>>4)*4+j
#pragma unroll
  for (int mi = 0; mi < 4; ++mi)
#pragma unroll
    for (int ni = 0; ni < 2; ++ni) {
      int cc = n0 + wn * 32 + ni * 16 + (lane & 15);
#pragma unroll
      for (int j = 0; j < 4; ++j) {
        int rr = m0 + wm * 64 + mi * 16 + ((lane >> 4) << 2) + j;
        float sc;
        if constexpr (MODE == 2) sc = gwt[rr]; else sc = 1.f;
        float g = silu_f(ac1[mi][ni][j]) * ac3[mi][ni][j] * sc;
        G[(size_t)rr * N + cc] = f2b(g);
      }
    }
}

// ---------- single-B bf16 GEMM: 128x256 tile, BK=64, 512 thr / 8 waves ----------
// wave tile 64x64; MODE 1: direct A, Cf = v*scale (fp32)
// MODE 4: direct A (gathered space), per-expert Bt segment, C->bf16
template <int MODE>
__global__ __launch_bounds__(512) void gemm_bt8(const unsigned short* __restrict__ A,
                                                const unsigned short* __restrict__ Bt,
                                                unsigned short* __restrict__ Cbf,
                                                float* __restrict__ Cf,
                                                int N, int K, int MB,
                                                const int* __restrict__ eoff,
                                                float scale) {
  __shared__ unsigned short sA[128 * 64];   // 16 KB
  __shared__ unsigned short sB[256 * 64];   // 32 KB

  int nwg = gridDim.x;
  int wg = xcd_swz(blockIdx.x, nwg);
  int mb, nb;
  tile_map(wg, MB, nwg / MB, mb, nb);
  int m0 = mb * 128;
  int n0 = nb * 256;

  const unsigned short* Bte = Bt;
  if constexpr (MODE == 4) {
    if (m0 >= eoff[NEXP]) return;
    int e = 0;
    while (m0 >= eoff[e + 1]) ++e;
    Bte = Bt + (size_t)e * N * K;
  }
  int tid = threadIdx.x, lane = tid & 63, wv = tid >> 6;
  int wm = wv >> 2, wn = wv & 3;            // wave tile: rows wm*64+, cols wn*64+
  f32x4 acc[4][4];
#pragma unroll
  for (int mi = 0; mi < 4; ++mi)
#pragma unroll
    for (int ni = 0; ni < 4; ++ni) acc[mi][ni] = (f32x4){0.f, 0.f, 0.f, 0.f};

  for (int kt = 0; kt < K; kt += 64) {
#pragma unroll
    for (int c = 0; c < 2; ++c) {           // stage A (16 KB)
      int bofs = (wv * 2 + c) * 1024 + lane * 16;
      int row = bofs >> 7;
      int sch = ((bofs >> 4) & 7) ^ (row & 7);
      gload16(A + (size_t)(m0 + row) * K + kt + sch * 8, &sA[(wv * 2 + c) * 512]);
    }
#pragma unroll
    for (int c = 0; c < 4; ++c) {           // stage B (32 KB, 256 rows)
      int bofs = (wv * 4 + c) * 1024 + lane * 16;
      int row = bofs >> 7;
      int sch = ((bofs >> 4) & 7) ^ (row & 7);
      gload16(Bte + (size_t)(n0 + row) * K + kt + sch * 8, &sB[(wv * 4 + c) * 512]);
    }
    __syncthreads();
#pragma unroll
    for (int kk = 0; kk < 2; ++kk) {
      bf16x8 af[4], bfv[4];
#pragma unroll
      for (int mi = 0; mi < 4; ++mi) {
        int row = wm * 64 + mi * 16 + (lane & 15);
        int ch = (kk * 4 + (lane >> 4)) ^ (row & 7);
        af[mi] = *(const bf16x8*)&sA[row * 64 + ch * 8];
      }
#pragma unroll
      for (int ni = 0; ni < 4; ++ni) {
        int row = wn * 64 + ni * 16 + (lane & 15);
        int ch = (kk * 4 + (lane >> 4)) ^ (row & 7);
        bfv[ni] = *(const bf16x8*)&sB[row * 64 + ch * 8];
      }
#pragma unroll
      for (int mi = 0; mi < 4; ++mi)
#pragma unroll
        for (int ni = 0; ni < 4; ++ni)
          acc[mi][ni] = __builtin_amdgcn_mfma_f32_16x16x32_bf16(af[mi], bfv[ni], acc[mi][ni], 0, 0, 0);
    }
    __syncthreads();
  }

#pragma unroll
  for (int mi = 0; mi < 4; ++mi)
#pragma unroll
    for (int ni = 0; ni < 4; ++ni) {
      int cc = n0 + wn * 64 + ni * 16 + (lane & 15);
#pragma unroll
      for (int j = 0; j < 4; ++j) {
        int rr = m0 + wm * 64 + mi * 16 + ((lane >> 4) << 2) + j;
        float v = acc[mi][ni][j];
        if constexpr (MODE == 1) Cf[(size_t)rr * N + cc] = v * scale;
        else Cbf[(size_t)rr * N + cc] = f2b(v);
      }
    }
}

extern "C" void kernel_launch(void* const* d_in, const int* in_sizes, int n_in,
                              void* d_out, int out_size, void* d_ws, size_t ws_size,
                              hipStream_t stream) {
  const float* x   = (const float*)d_in[0];
  const float* wr  = (const float*)d_in[1];
  const float* we1 = (const float*)d_in[2];
  const float* we3 = (const float*)d_in[3];
  const float* we2 = (const float*)d_in[4];
  const float* ws1 = (const float*)d_in[5];
  const float* ws3 = (const float*)d_in[6];
  const float* ws2 = (const float*)d_in[7];
  float* out = (float*)d_out;   // fp32 output per reference dtype

  char* p = (char*)d_ws;
  auto take = [&](size_t bytes) { char* r = p; p += (bytes + 255) & ~(size_t)255; return r; };
  unsigned short* xbf   = (unsigned short*)take((size_t)TTOK * DDIM * 2);    // 16 MiB
  unsigned short* ehg   = (unsigned short*)take((size_t)CAPR * HDIM * 2);    // 36 MiB (expert g)
  unsigned short* gsh   = (unsigned short*)take((size_t)TTOK * HSDIM * 2);   // 32 MiB (shared g)
  unsigned short* ecout = (unsigned short*)take((size_t)CAPR * DDIM * 2);    // 72 MiB
  unsigned short* twArena = (unsigned short*)take((size_t)NEXP * HDIM * DDIM * 2);  // 64 MiB
  float* topw = (float*)take((size_t)TTOK * 4 * 4);
  int*   topi = (int*)take((size_t)TTOK * 4 * 4);
  int*   gtok = (int*)take((size_t)CAPR * 4);
  float* gwt  = (float*)take((size_t)CAPR * 4);
  int*   posmap = (int*)take((size_t)TTOK * 4 * 4);
  int*   ibuf = (int*)take(256);   // [0:16) counts, [16:32) cursors, [32:49) eoff
  if ((size_t)(p - (char*)d_ws) > ws_size) return;  // ws too small -> visible failure

  unsigned short* twA = twArena;                                   // first 32 MiB
  unsigned short* twB = twArena + (size_t)8 * DDIM * HDIM;         // second 32 MiB
  // we3^T (64 MiB) aliases gsh(32) + first 32 MiB of ecout — both dead in expert GEMM1 phase;
  // ecout's overlap region is rewritten only by gemm_bt8<4> afterwards.
  unsigned short* we3t = gsh;

  int* counts  = ibuf;
  int* cursors = ibuf + 16;
  int* eoff    = ibuf + 32;

  // ---- prep: x -> bf16; router; permutation ----
  cvt_bf16_kernel<<<TTOK * DDIM / 8 / 256, 256, 0, stream>>>(x, xbf, TTOK * DDIM / 8);
  router_kernel<<<TTOK / 4, 256, 0, stream>>>(x, wr, topw, topi);
  zero_kernel<<<1, 64, 0, stream>>>(ibuf);
  count_kernel<<<TTOK * 4 / 256, 256, 0, stream>>>(topi, counts, TTOK * 4);
  offsets_kernel<<<1, 64, 0, stream>>>(counts, eoff);
  prefill_kernel<<<CAPR / 256, 256, 0, stream>>>(gtok, gwt, CAPR);
  scatter_kernel<<<TTOK * 4 / 256, 256, 0, stream>>>(topi, topw, eoff, cursors, gtok, gwt, posmap, TTOK * 4);

  // ---- shared MLP: gsh = silu(x@ws1)*(x@ws3); out = 0.2 * gsh @ ws2 ----
  transpose_f2b<<<dim3(HSDIM / 64, DDIM / 64, 1), 256, 0, stream>>>(ws1, twA, DDIM, HSDIM);
  transpose_f2b<<<dim3(HSDIM / 64, DDIM / 64, 1), 256, 0, stream>>>(ws3, twB, DDIM, HSDIM);
  gemm_dual<0><<<(TTOK / 128) * (HSDIM / 128), 512, 0, stream>>>(xbf, twA, twB, gsh, HSDIM, DDIM,
                                                                 TTOK / 128, nullptr, nullptr, nullptr);
  transpose_f2b<<<dim3(DDIM / 64, HSDIM / 64, 1), 256, 0, stream>>>(ws2, twA, HSDIM, DDIM);
  gemm_bt8<1><<<(TTOK / 128) * (DDIM / 256), 512, 0, stream>>>(gsh, twA, nullptr, out, DDIM, HSDIM,
                                                               TTOK / 128, nullptr, 0.2f);

  // ---- experts (single merged launch over all 16): ehg = silu(xg@we1)*(xg@we3)*gwt ----
  transpose_f2b<<<dim3(HDIM / 64, DDIM / 64, NEXP), 256, 0, stream>>>(we1, twArena, DDIM, HDIM);
  transpose_f2b<<<dim3(HDIM / 64, DDIM / 64, NEXP), 256, 0, stream>>>(we3, we3t, DDIM, HDIM);
  gemm_dual<2><<<(CAPR / 128) * (HDIM / 128), 512, 0, stream>>>(xbf, twArena, we3t, ehg, HDIM, DDIM,
                                                                CAPR / 128, gtok, gwt, eoff);
  // expert GEMM2: ecout = ehg @ we2 (per-expert), bf16 at gathered rows
  transpose_f2b<<<dim3(DDIM / 64, HDIM / 64, NEXP), 256, 0, stream>>>(we2, twArena, HDIM, DDIM);
  gemm_bt8<4><<<(CAPR / 128) * (DDIM / 256), 512, 0, stream>>>(ehg, twArena, ecout, nullptr, DDIM, HDIM,
                                                               CAPR / 128, eoff, 0.f);

  // ---- out = 0.2*shared + sum_k ecout[pos[t][k]] ----
  combine_kernel<<<TTOK * DDIM / 8 / 256, 256, 0, stream>>>(ecout, posmap, out, TTOK * DDIM / 8);
}

// Round 10
// 787.131 us; speedup vs baseline: 1.8028x; 1.0383x over previous
//
#include <hip/hip_runtime.h>
#include <stdint.h>

// Problem constants (B=2,S=2048 -> T=4096 tokens)
#define TTOK  4096
#define DDIM  2048
#define NEXP  16
#define HDIM  1024
#define HSDIM 4096
#define CAPR  18432   // 4096*4 + 16*128 padded capacity (128-aligned segments)

typedef __bf16 bf16x8 __attribute__((ext_vector_type(8)));
typedef float  f32x4  __attribute__((ext_vector_type(4)));

__device__ __forceinline__ unsigned short f2b(float f) {
  union { float f; unsigned int i; } v; v.f = f;
  unsigned int r = (v.i + 0x7fffu + ((v.i >> 16) & 1u)) >> 16;
  return (unsigned short)r;
}
__device__ __forceinline__ float b2f(unsigned short u) {
  union { unsigned int i; float f; } v; v.i = ((unsigned int)u) << 16; return v.f;
}
__device__ __forceinline__ float silu_f(float x) { return x / (1.f + __expf(-x)); }

// async global->LDS, 16B per lane. LDS dest must be wave-uniform (HW adds lane*16).
__device__ __forceinline__ void gload16(const void* g, void* l) {
  __builtin_amdgcn_global_load_lds(
      (const __attribute__((address_space(1))) unsigned int*)(uintptr_t)g,
      (__attribute__((address_space(3))) unsigned int*)(uintptr_t)l,
      16, 0, 0);
}

// bijective XCD-aware swizzle (m204 form), 1D grid
__device__ __forceinline__ int xcd_swz(int bid, int nwg) {
  int q = nwg >> 3, r = nwg & 7;
  int xcd = bid & 7, off = bid >> 3;
  return (xcd < r ? xcd * (q + 1) : r * (q + 1) + (xcd - r) * q) + off;
}

// supertile mapping: 4m x 8n supertiles, n-fastest inside.
// requires MB%4==0 && NB%8==0 (true for all launches here).
__device__ __forceinline__ void tile_map(int wg, int MB, int NB, int& mb, int& nb) {
  int st = wg >> 5;            // supertile index (32 wgs each)
  int in = wg & 31;
  int sm = MB >> 2;            // supertiles along m
  int stm = st % sm;
  int stn = st / sm;
  mb = stm * 4 + (in >> 3);
  nb = stn * 8 + (in & 7);
}

// ---------- transpose fp32 [R][C] -> bf16 [C][R]; two source/dest pairs ----------
// blockIdx.z < zsplit -> (inA -> outA, matrix z); else (inB -> outB, matrix z-zsplit)
// float4 global reads -> LDS; ushort8 (16B) packed global writes.
__global__ __launch_bounds__(256) void transpose_f2b2(const float* __restrict__ inA,
                                                      const float* __restrict__ inB,
                                                      unsigned short* __restrict__ outA,
                                                      unsigned short* __restrict__ outB,
                                                      int R, int C, int zsplit) {
  __shared__ unsigned short t[64][68];
  int z = blockIdx.z;
  const float* in = (z < zsplit) ? inA : inB;
  unsigned short* out = (z < zsplit) ? outA : outB;
  int zm = (z < zsplit) ? z : z - zsplit;
  size_t zo = (size_t)zm * (size_t)R * C;
  int c0 = blockIdx.x * 64, r0 = blockIdx.y * 64;
  int tid = threadIdx.x;
#pragma unroll
  for (int p = 0; p < 4; ++p) {
    int id = p * 256 + tid;
    int r = id >> 4;               // 0..63
    int c4 = (id & 15) * 4;        // 0,4,..,60
    float4 v = *(const float4*)&in[zo + (size_t)(r0 + r) * C + c0 + c4];
    ushort4 w = { f2b(v.x), f2b(v.y), f2b(v.z), f2b(v.w) };
    *(ushort4*)&t[r][c4] = w;
  }
  __syncthreads();
#pragma unroll
  for (int p = 0; p < 2; ++p) {
    int id = p * 256 + tid;        // 0..511
    int c = id >> 3;               // 0..63
    int r8 = (id & 7) * 8;         // 0,8,..,56
    unsigned p0 = (unsigned)t[r8 + 0][c] | ((unsigned)t[r8 + 1][c] << 16);
    unsigned p1 = (unsigned)t[r8 + 2][c] | ((unsigned)t[r8 + 3][c] << 16);
    unsigned p2 = (unsigned)t[r8 + 4][c] | ((unsigned)t[r8 + 5][c] << 16);
    unsigned p3 = (unsigned)t[r8 + 6][c] | ((unsigned)t[r8 + 7][c] << 16);
    uint4 o = { p0, p1, p2, p3 };
    *(uint4*)&out[zo + (size_t)(c0 + c) * R + r0 + r8] = o;
  }
}

// ---------- router: logits, top-4 by logit, renormalized weights; also emits xbf ----------
// (R6-proven loop: scalar x read + float4 w read; added: bf16 store of x)
__global__ __launch_bounds__(256) void router_kernel(const float* __restrict__ x, const float* __restrict__ wr,
                                                     float* __restrict__ topw, int* __restrict__ topi,
                                                     unsigned short* __restrict__ xbf) {
  int tok = blockIdx.x * 4 + (threadIdx.x >> 6);
  int lane = threadIdx.x & 63;
  const float* xr = x + (size_t)tok * DDIM;
  unsigned short* xb = xbf + (size_t)tok * DDIM;
  float acc[NEXP];
#pragma unroll
  for (int e = 0; e < NEXP; ++e) acc[e] = 0.f;
  for (int it = 0; it < DDIM / 64; ++it) {
    int d = it * 64 + lane;
    float xv = xr[d];
    xb[d] = f2b(xv);                       // fused x -> bf16
    const float4* w4 = (const float4*)(wr + (size_t)d * NEXP);
    float4 w0 = w4[0], w1 = w4[1], w2 = w4[2], w3 = w4[3];
    acc[0] += xv * w0.x; acc[1] += xv * w0.y; acc[2] += xv * w0.z; acc[3] += xv * w0.w;
    acc[4] += xv * w1.x; acc[5] += xv * w1.y; acc[6] += xv * w1.z; acc[7] += xv * w1.w;
    acc[8] += xv * w2.x; acc[9] += xv * w2.y; acc[10] += xv * w2.z; acc[11] += xv * w2.w;
    acc[12] += xv * w3.x; acc[13] += xv * w3.y; acc[14] += xv * w3.z; acc[15] += xv * w3.w;
  }
#pragma unroll
  for (int e = 0; e < NEXP; ++e) {
#pragma unroll
    for (int off = 32; off > 0; off >>= 1) acc[e] += __shfl_xor(acc[e], off);
  }
  unsigned used = 0u;
  float lv[4]; int si[4];
#pragma unroll
  for (int k = 0; k < 4; ++k) {
    float best = -3.4e38f; int bi = 0;
    for (int e = 0; e < NEXP; ++e) {
      if (!((used >> e) & 1u) && acc[e] > best) { best = acc[e]; bi = e; }
    }
    used |= 1u << bi; lv[k] = best; si[k] = bi;
  }
  if (lane == 0) {
    float m = lv[0], s = 0.f, w[4];
#pragma unroll
    for (int k = 0; k < 4; ++k) { w[k] = __expf(lv[k] - m); s += w[k]; }
    float inv = 1.f / s;
#pragma unroll
    for (int k = 0; k < 4; ++k) { topw[tok * 4 + k] = w[k] * inv; topi[tok * 4 + k] = si[k]; }
  }
}

// ---------- tiny bookkeeping kernels ----------
__global__ void zero_kernel(int* b) { if (threadIdx.x < 64) b[threadIdx.x] = 0; }

__global__ void count_kernel(const int* __restrict__ topi, int* counts, int n) {
  int i = blockIdx.x * 256 + threadIdx.x;
  if (i < n) atomicAdd(&counts[topi[i]], 1);
}

__global__ void offsets_kernel(const int* counts, int* eoff) {
  if (threadIdx.x == 0 && blockIdx.x == 0) {
    int o = 0;
    for (int e = 0; e < NEXP; ++e) { eoff[e] = o; o += (counts[e] + 127) & ~127; }
    eoff[NEXP] = o;
  }
}

__global__ void prefill_kernel(int* gtok, float* gwt, int cap) {
  int i = blockIdx.x * 256 + threadIdx.x;
  if (i < cap) { gtok[i] = 0; gwt[i] = 0.f; }
}

__global__ void scatter_kernel(const int* __restrict__ topi, const float* __restrict__ topw,
                               const int* __restrict__ eoff, int* cursors,
                               int* gtok, float* gwt, int* posmap, int n) {
  int i = blockIdx.x * 256 + threadIdx.x;
  if (i >= n) return;
  int e = topi[i];
  int pos = eoff[e] + atomicAdd(&cursors[e], 1);
  gtok[pos] = i >> 2;
  gwt[pos] = topw[i] * 0.8f;   // fold k/(k+1)
  posmap[i] = pos;
}

// ---------- final combine: out = 0.2*shared (already in out) + sum_k ecout[pos[t][k]] ----------
__global__ __launch_bounds__(256) void combine_kernel(const unsigned short* __restrict__ ecout,
                                                      const int* __restrict__ posmap,
                                                      float* __restrict__ out, int n8) {
  int i = blockIdx.x * 256 + threadIdx.x;   // one thread per 8 d-elems
  if (i >= n8) return;
  int t = i >> 8;                            // DDIM/8 = 256 chunks per token
  int c = i & 255;
  int4 pv = *(const int4*)&posmap[t * 4];
  float s[8];
  float4 o0 = ((const float4*)out)[(size_t)i * 2];
  float4 o1 = ((const float4*)out)[(size_t)i * 2 + 1];
  s[0]=o0.x; s[1]=o0.y; s[2]=o0.z; s[3]=o0.w; s[4]=o1.x; s[5]=o1.y; s[6]=o1.z; s[7]=o1.w;
  int pos[4] = {pv.x, pv.y, pv.z, pv.w};
#pragma unroll
  for (int k = 0; k < 4; ++k) {
    uint4 v = ((const uint4*)(ecout + (size_t)pos[k] * DDIM))[c];
    unsigned* pw = (unsigned*)&v;
#pragma unroll
    for (int w = 0; w < 4; ++w) {
      s[w * 2]     += b2f((unsigned short)(pw[w] & 0xffffu));
      s[w * 2 + 1] += b2f((unsigned short)(pw[w] >> 16));
    }
  }
  float4 r0 = {s[0], s[1], s[2], s[3]}, r1 = {s[4], s[5], s[6], s[7]};
  ((float4*)out)[(size_t)i * 2] = r0;
  ((float4*)out)[(size_t)i * 2 + 1] = r1;
}

// =====================================================================
// Dual-B SwiGLU GEMM: G[M,N] = silu(A@W1^T) * (A@W3^T) * scale, 128x128 tile,
// BK=64, 512 thr / 8 waves (wave tile 64x32). W1,W3 are [N][K] bf16.
// MODE 0: direct A rows, single weight pair, scale=1
// MODE 2: A rows gathered via gtok[], per-expert weights, scale=gwt[row]
// =====================================================================
template <int MODE>
__global__ __launch_bounds__(512) void gemm_dual(const unsigned short* __restrict__ A,
                                                 const unsigned short* __restrict__ W1,
                                                 const unsigned short* __restrict__ W3,
                                                 unsigned short* __restrict__ G,
                                                 int N, int K, int MB,
                                                 const int* __restrict__ gtok,
                                                 const float* __restrict__ gwt,
                                                 const int* __restrict__ eoff) {
  __shared__ unsigned short sA[128 * 64];
  __shared__ unsigned short s1[128 * 64];
  __shared__ unsigned short s3[128 * 64];
  __shared__ int sIdx[128];

  int nwg = gridDim.x;
  int wg = xcd_swz(blockIdx.x, nwg);
  int mb, nb;
  tile_map(wg, MB, nwg / MB, mb, nb);
  int m0 = mb * 128;
  int n0 = nb * 128;

  const unsigned short* W1e = W1;
  const unsigned short* W3e = W3;
  if constexpr (MODE == 2) {
    if (m0 >= eoff[NEXP]) return;              // block-uniform
    int e = 0;
    while (m0 >= eoff[e + 1]) ++e;
    size_t wofs = (size_t)e * N * K;
    W1e += wofs; W3e += wofs;
  }

  int tid = threadIdx.x, lane = tid & 63, wv = tid >> 6;
  if constexpr (MODE == 2) {
    if (tid < 128) sIdx[tid] = gtok[m0 + tid];
    __syncthreads();
  }

  int wm = wv >> 2, wn = wv & 3;             // wave tile: rows wm*64+, cols wn*32+
  f32x4 ac1[4][2], ac3[4][2];
#pragma unroll
  for (int mi = 0; mi < 4; ++mi)
#pragma unroll
    for (int ni = 0; ni < 2; ++ni) { ac1[mi][ni] = (f32x4){0,0,0,0}; ac3[mi][ni] = (f32x4){0,0,0,0}; }

  for (int kt = 0; kt < K; kt += 64) {
    // stage A, W1, W3 tiles: [128 rows][64 k] bf16, XOR-swizzled via pre-swizzled source
#pragma unroll
    for (int c = 0; c < 2; ++c) {
      int bofs = (wv * 2 + c) * 1024 + lane * 16;          // byte offset within tile
      int row = bofs >> 7;                                 // 128 B per row
      int sch = ((bofs >> 4) & 7) ^ (row & 7);             // source chunk (inverse swizzle)
      int ar;
      if constexpr (MODE == 2) ar = sIdx[row]; else ar = m0 + row;
      gload16(A   + (size_t)ar * K        + kt + sch * 8, &sA[(wv * 2 + c) * 512]);
      gload16(W1e + (size_t)(n0 + row) * K + kt + sch * 8, &s1[(wv * 2 + c) * 512]);
      gload16(W3e + (size_t)(n0 + row) * K + kt + sch * 8, &s3[(wv * 2 + c) * 512]);
    }
    __syncthreads();
#pragma unroll
    for (int kk = 0; kk < 2; ++kk) {
      bf16x8 af[4], b1[2], b3[2];
#pragma unroll
      for (int mi = 0; mi < 4; ++mi) {
        int row = wm * 64 + mi * 16 + (lane & 15);
        int ch = (kk * 4 + (lane >> 4)) ^ (row & 7);
        af[mi] = *(const bf16x8*)&sA[row * 64 + ch * 8];
      }
#pragma unroll
      for (int ni = 0; ni < 2; ++ni) {
        int row = wn * 32 + ni * 16 + (lane & 15);
        int ch = (kk * 4 + (lane >> 4)) ^ (row & 7);
        b1[ni] = *(const bf16x8*)&s1[row * 64 + ch * 8];
        b3[ni] = *(const bf16x8*)&s3[row * 64 + ch * 8];
      }
#pragma unroll
      for (int mi = 0; mi < 4; ++mi)
#pragma unroll
        for (int ni = 0; ni < 2; ++ni) {
          ac1[mi][ni] = __builtin_amdgcn_mfma_f32_16x16x32_bf16(af[mi], b1[ni], ac1[mi][ni], 0, 0, 0);
          ac3[mi][ni] = __builtin_amdgcn_mfma_f32_16x16x32_bf16(af[mi], b3[ni], ac3[mi][ni], 0, 0, 0);
        }
    }
    __syncthreads();
  }

  // epilogue: g = silu(c1)*c3*scale ; C/D layout col=lane&15, row=(lane>>4)*4+j
#pragma unroll
  for (int mi = 0; mi < 4; ++mi)
#pragma unroll
    for (int ni = 0; ni < 2; ++ni) {
      int cc = n0 + wn * 32 + ni * 16 + (lane & 15);
#pragma unroll
      for (int j = 0; j < 4; ++j) {
        int rr = m0 + wm * 64 + mi * 16 + ((lane >> 4) << 2) + j;
        float sc;
        if constexpr (MODE == 2) sc = gwt[rr]; else sc = 1.f;
        float g = silu_f(ac1[mi][ni][j]) * ac3[mi][ni][j] * sc;
        G[(size_t)rr * N + cc] = f2b(g);
      }
    }
}

// ---------- single-B bf16 GEMM: 128x256 tile, BK=64, 512 thr / 8 waves ----------
// wave tile 64x64; MODE 1: direct A, Cf = v*scale (fp32)
// MODE 4: direct A (gathered space), per-expert Bt segment, C->bf16
template <int MODE>
__global__ __launch_bounds__(512) void gemm_bt8(const unsigned short* __restrict__ A,
                                                const unsigned short* __restrict__ Bt,
                                                unsigned short* __restrict__ Cbf,
                                                float* __restrict__ Cf,
                                                int N, int K, int MB,
                                                const int* __restrict__ eoff,
                                                float scale) {
  __shared__ unsigned short sA[128 * 64];   // 16 KB
  __shared__ unsigned short sB[256 * 64];   // 32 KB

  int nwg = gridDim.x;
  int wg = xcd_swz(blockIdx.x, nwg);
  int mb, nb;
  tile_map(wg, MB, nwg / MB, mb, nb);
  int m0 = mb * 128;
  int n0 = nb * 256;

  const unsigned short* Bte = Bt;
  if constexpr (MODE == 4) {
    if (m0 >= eoff[NEXP]) return;
    int e = 0;
    while (m0 >= eoff[e + 1]) ++e;
    Bte = Bt + (size_t)e * N * K;
  }
  int tid = threadIdx.x, lane = tid & 63, wv = tid >> 6;
  int wm = wv >> 2, wn = wv & 3;            // wave tile: rows wm*64+, cols wn*64+
  f32x4 acc[4][4];
#pragma unroll
  for (int mi = 0; mi < 4; ++mi)
#pragma unroll
    for (int ni = 0; ni < 4; ++ni) acc[mi][ni] = (f32x4){0.f, 0.f, 0.f, 0.f};

  for (int kt = 0; kt < K; kt += 64) {
#pragma unroll
    for (int c = 0; c < 2; ++c) {           // stage A (16 KB)
      int bofs = (wv * 2 + c) * 1024 + lane * 16;
      int row = bofs >> 7;
      int sch = ((bofs >> 4) & 7) ^ (row & 7);
      gload16(A + (size_t)(m0 + row) * K + kt + sch * 8, &sA[(wv * 2 + c) * 512]);
    }
#pragma unroll
    for (int c = 0; c < 4; ++c) {           // stage B (32 KB, 256 rows)
      int bofs = (wv * 4 + c) * 1024 + lane * 16;
      int row = bofs >> 7;
      int sch = ((bofs >> 4) & 7) ^ (row & 7);
      gload16(Bte + (size_t)(n0 + row) * K + kt + sch * 8, &sB[(wv * 4 + c) * 512]);
    }
    __syncthreads();
#pragma unroll
    for (int kk = 0; kk < 2; ++kk) {
      bf16x8 af[4], bfv[4];
#pragma unroll
      for (int mi = 0; mi < 4; ++mi) {
        int row = wm * 64 + mi * 16 + (lane & 15);
        int ch = (kk * 4 + (lane >> 4)) ^ (row & 7);
        af[mi] = *(const bf16x8*)&sA[row * 64 + ch * 8];
      }
#pragma unroll
      for (int ni = 0; ni < 4; ++ni) {
        int row = wn * 64 + ni * 16 + (lane & 15);
        int ch = (kk * 4 + (lane >> 4)) ^ (row & 7);
        bfv[ni] = *(const bf16x8*)&sB[row * 64 + ch * 8];
      }
#pragma unroll
      for (int mi = 0; mi < 4; ++mi)
#pragma unroll
        for (int ni = 0; ni < 4; ++ni)
          acc[mi][ni] = __builtin_amdgcn_mfma_f32_16x16x32_bf16(af[mi], bfv[ni], acc[mi][ni], 0, 0, 0);
    }
    __syncthreads();
  }

#pragma unroll
  for (int mi = 0; mi < 4; ++mi)
#pragma unroll
    for (int ni = 0; ni < 4; ++ni) {
      int cc = n0 + wn * 64 + ni * 16 + (lane & 15);
#pragma unroll
      for (int j = 0; j < 4; ++j) {
        int rr = m0 + wm * 64 + mi * 16 + ((lane >> 4) << 2) + j;
        float v = acc[mi][ni][j];
        if constexpr (MODE == 1) Cf[(size_t)rr * N + cc] = v * scale;
        else Cbf[(size_t)rr * N + cc] = f2b(v);
      }
    }
}

extern "C" void kernel_launch(void* const* d_in, const int* in_sizes, int n_in,
                              void* d_out, int out_size, void* d_ws, size_t ws_size,
                              hipStream_t stream) {
  const float* x   = (const float*)d_in[0];
  const float* wr  = (const float*)d_in[1];
  const float* we1 = (const float*)d_in[2];
  const float* we3 = (const float*)d_in[3];
  const float* we2 = (const float*)d_in[4];
  const float* ws1 = (const float*)d_in[5];
  const float* ws3 = (const float*)d_in[6];
  const float* ws2 = (const float*)d_in[7];
  float* out = (float*)d_out;   // fp32 output per reference dtype

  char* p = (char*)d_ws;
  auto take = [&](size_t bytes) { char* r = p; p += (bytes + 255) & ~(size_t)255; return r; };
  unsigned short* xbf   = (unsigned short*)take((size_t)TTOK * DDIM * 2);    // 16 MiB
  unsigned short* ehg   = (unsigned short*)take((size_t)CAPR * HDIM * 2);    // 36 MiB (expert g)
  unsigned short* gsh   = (unsigned short*)take((size_t)TTOK * HSDIM * 2);   // 32 MiB (shared g)
  unsigned short* ecout = (unsigned short*)take((size_t)CAPR * DDIM * 2);    // 72 MiB
  unsigned short* twArena = (unsigned short*)take((size_t)NEXP * HDIM * DDIM * 2);  // 64 MiB
  float* topw = (float*)take((size_t)TTOK * 4 * 4);
  int*   topi = (int*)take((size_t)TTOK * 4 * 4);
  int*   gtok = (int*)take((size_t)CAPR * 4);
  float* gwt  = (float*)take((size_t)CAPR * 4);
  int*   posmap = (int*)take((size_t)TTOK * 4 * 4);
  int*   ibuf = (int*)take(256);   // [0:16) counts, [16:32) cursors, [32:49) eoff
  if ((size_t)(p - (char*)d_ws) > ws_size) return;  // ws too small -> visible failure

  unsigned short* twA = twArena;                                   // first 32 MiB
  unsigned short* twB = twArena + (size_t)8 * DDIM * HDIM;         // second 32 MiB
  // we3^T (64 MiB) aliases gsh(32) + first 32 MiB of ecout — both dead in expert GEMM1 phase;
  // ecout's overlap region is rewritten only by gemm_bt8<4> afterwards.
  unsigned short* we3t = gsh;

  int* counts  = ibuf;
  int* cursors = ibuf + 16;
  int* eoff    = ibuf + 32;

  // ---- prep: router (emits xbf too); permutation ----
  router_kernel<<<TTOK / 4, 256, 0, stream>>>(x, wr, topw, topi, xbf);
  zero_kernel<<<1, 64, 0, stream>>>(ibuf);
  count_kernel<<<TTOK * 4 / 256, 256, 0, stream>>>(topi, counts, TTOK * 4);
  offsets_kernel<<<1, 64, 0, stream>>>(counts, eoff);
  prefill_kernel<<<CAPR / 256, 256, 0, stream>>>(gtok, gwt, CAPR);
  scatter_kernel<<<TTOK * 4 / 256, 256, 0, stream>>>(topi, topw, eoff, cursors, gtok, gwt, posmap, TTOK * 4);

  // ---- shared MLP: gsh = silu(x@ws1)*(x@ws3); out = 0.2 * gsh @ ws2 ----
  transpose_f2b2<<<dim3(HSDIM / 64, DDIM / 64, 2), 256, 0, stream>>>(ws1, ws3, twA, twB, DDIM, HSDIM, 1);
  gemm_dual<0><<<(TTOK / 128) * (HSDIM / 128), 512, 0, stream>>>(xbf, twA, twB, gsh, HSDIM, DDIM,
                                                                 TTOK / 128, nullptr, nullptr, nullptr);
  transpose_f2b2<<<dim3(DDIM / 64, HSDIM / 64, 1), 256, 0, stream>>>(ws2, ws2, twA, twA, HSDIM, DDIM, 1);
  gemm_bt8<1><<<(TTOK / 128) * (DDIM / 256), 512, 0, stream>>>(gsh, twA, nullptr, out, DDIM, HSDIM,
                                                               TTOK / 128, nullptr, 0.2f);

  // ---- experts (single merged launch over all 16): ehg = silu(xg@we1)*(xg@we3)*gwt ----
  transpose_f2b2<<<dim3(HDIM / 64, DDIM / 64, 2 * NEXP), 256, 0, stream>>>(we1, we3, twArena, we3t,
                                                                           DDIM, HDIM, NEXP);
  gemm_dual<2><<<(CAPR / 128) * (HDIM / 128), 512, 0, stream>>>(xbf, twArena, we3t, ehg, HDIM, DDIM,
                                                                CAPR / 128, gtok, gwt, eoff);
  // expert GEMM2: ecout = ehg @ we2 (per-expert), bf16 at gathered rows
  transpose_f2b2<<<dim3(DDIM / 64, HDIM / 64, NEXP), 256, 0, stream>>>(we2, we2, twArena, twArena,
                                                                       HDIM, DDIM, NEXP);
  gemm_bt8<4><<<(CAPR / 128) * (DDIM / 256), 512, 0, stream>>>(ehg, twArena, ecout, nullptr, DDIM, HDIM,
                                                               CAPR / 128, eoff, 0.f);

  // ---- out = 0.2*shared + sum_k ecout[pos[t][k]] ----
  combine_kernel<<<TTOK * DDIM / 8 / 256, 256, 0, stream>>>(ecout, posmap, out, TTOK * DDIM / 8);
}

// Round 11
// 778.843 us; speedup vs baseline: 1.8220x; 1.0106x over previous
//
#include <hip/hip_runtime.h>
#include <stdint.h>

// Problem constants (B=2,S=2048 -> T=4096 tokens)
#define TTOK  4096
#define DDIM  2048
#define NEXP  16
#define HDIM  1024
#define HSDIM 4096
#define CAPR  18432   // 4096*4 + 16*128 padded capacity (128-aligned segments)

typedef __bf16 bf16x8 __attribute__((ext_vector_type(8)));
typedef float  f32x4  __attribute__((ext_vector_type(4)));

__device__ __forceinline__ unsigned short f2b(float f) {
  union { float f; unsigned int i; } v; v.f = f;
  unsigned int r = (v.i + 0x7fffu + ((v.i >> 16) & 1u)) >> 16;
  return (unsigned short)r;
}
__device__ __forceinline__ float b2f(unsigned short u) {
  union { unsigned int i; float f; } v; v.i = ((unsigned int)u) << 16; return v.f;
}
__device__ __forceinline__ float silu_f(float x) { return x / (1.f + __expf(-x)); }

// async global->LDS, 16B per lane. LDS dest must be wave-uniform (HW adds lane*16).
__device__ __forceinline__ void gload16(const void* g, void* l) {
  __builtin_amdgcn_global_load_lds(
      (const __attribute__((address_space(1))) unsigned int*)(uintptr_t)g,
      (__attribute__((address_space(3))) unsigned int*)(uintptr_t)l,
      16, 0, 0);
}

// bijective XCD-aware swizzle (m204 form), 1D grid
__device__ __forceinline__ int xcd_swz(int bid, int nwg) {
  int q = nwg >> 3, r = nwg & 7;
  int xcd = bid & 7, off = bid >> 3;
  return (xcd < r ? xcd * (q + 1) : r * (q + 1) + (xcd - r) * q) + off;
}

// supertile mapping: 4m x 8n supertiles, n-fastest inside.
// requires MB%4==0 && NB%8==0 (true for all launches here).
__device__ __forceinline__ void tile_map(int wg, int MB, int NB, int& mb, int& nb) {
  int st = wg >> 5;            // supertile index (32 wgs each)
  int in = wg & 31;
  int sm = MB >> 2;            // supertiles along m
  int stm = st % sm;
  int stn = st / sm;
  mb = stm * 4 + (in >> 3);
  nb = stn * 8 + (in & 7);
}

// ---------- transpose fp32 [R][C] -> bf16 [C][R]; two source/dest pairs ----------
// blockIdx.z < zsplit -> (inA -> outA, matrix z); else (inB -> outB, matrix z-zsplit)
// float4 global reads -> LDS; ushort8 (16B) packed global writes.
__global__ __launch_bounds__(256) void transpose_f2b2(const float* __restrict__ inA,
                                                      const float* __restrict__ inB,
                                                      unsigned short* __restrict__ outA,
                                                      unsigned short* __restrict__ outB,
                                                      int R, int C, int zsplit) {
  __shared__ unsigned short t[64][68];
  int z = blockIdx.z;
  const float* in = (z < zsplit) ? inA : inB;
  unsigned short* out = (z < zsplit) ? outA : outB;
  int zm = (z < zsplit) ? z : z - zsplit;
  size_t zo = (size_t)zm * (size_t)R * C;
  int c0 = blockIdx.x * 64, r0 = blockIdx.y * 64;
  int tid = threadIdx.x;
#pragma unroll
  for (int p = 0; p < 4; ++p) {
    int id = p * 256 + tid;
    int r = id >> 4;               // 0..63
    int c4 = (id & 15) * 4;        // 0,4,..,60
    float4 v = *(const float4*)&in[zo + (size_t)(r0 + r) * C + c0 + c4];
    ushort4 w = { f2b(v.x), f2b(v.y), f2b(v.z), f2b(v.w) };
    *(ushort4*)&t[r][c4] = w;
  }
  __syncthreads();
#pragma unroll
  for (int p = 0; p < 2; ++p) {
    int id = p * 256 + tid;        // 0..511
    int c = id >> 3;               // 0..63
    int r8 = (id & 7) * 8;         // 0,8,..,56
    unsigned p0 = (unsigned)t[r8 + 0][c] | ((unsigned)t[r8 + 1][c] << 16);
    unsigned p1 = (unsigned)t[r8 + 2][c] | ((unsigned)t[r8 + 3][c] << 16);
    unsigned p2 = (unsigned)t[r8 + 4][c] | ((unsigned)t[r8 + 5][c] << 16);
    unsigned p3 = (unsigned)t[r8 + 6][c] | ((unsigned)t[r8 + 7][c] << 16);
    uint4 o = { p0, p1, p2, p3 };
    *(uint4*)&out[zo + (size_t)(c0 + c) * R + r0 + r8] = o;
  }
}

// ---------- router: logits, top-4 by logit, renormalized weights; also emits xbf ----------
// (R6-proven loop: scalar x read + float4 w read; added: bf16 store of x)
__global__ __launch_bounds__(256) void router_kernel(const float* __restrict__ x, const float* __restrict__ wr,
                                                     float* __restrict__ topw, int* __restrict__ topi,
                                                     unsigned short* __restrict__ xbf) {
  int tok = blockIdx.x * 4 + (threadIdx.x >> 6);
  int lane = threadIdx.x & 63;
  const float* xr = x + (size_t)tok * DDIM;
  unsigned short* xb = xbf + (size_t)tok * DDIM;
  float acc[NEXP];
#pragma unroll
  for (int e = 0; e < NEXP; ++e) acc[e] = 0.f;
  for (int it = 0; it < DDIM / 64; ++it) {
    int d = it * 64 + lane;
    float xv = xr[d];
    xb[d] = f2b(xv);                       // fused x -> bf16
    const float4* w4 = (const float4*)(wr + (size_t)d * NEXP);
    float4 w0 = w4[0], w1 = w4[1], w2 = w4[2], w3 = w4[3];
    acc[0] += xv * w0.x; acc[1] += xv * w0.y; acc[2] += xv * w0.z; acc[3] += xv * w0.w;
    acc[4] += xv * w1.x; acc[5] += xv * w1.y; acc[6] += xv * w1.z; acc[7] += xv * w1.w;
    acc[8] += xv * w2.x; acc[9] += xv * w2.y; acc[10] += xv * w2.z; acc[11] += xv * w2.w;
    acc[12] += xv * w3.x; acc[13] += xv * w3.y; acc[14] += xv * w3.z; acc[15] += xv * w3.w;
  }
#pragma unroll
  for (int e = 0; e < NEXP; ++e) {
#pragma unroll
    for (int off = 32; off > 0; off >>= 1) acc[e] += __shfl_xor(acc[e], off);
  }
  unsigned used = 0u;
  float lv[4]; int si[4];
#pragma unroll
  for (int k = 0; k < 4; ++k) {
    float best = -3.4e38f; int bi = 0;
    for (int e = 0; e < NEXP; ++e) {
      if (!((used >> e) & 1u) && acc[e] > best) { best = acc[e]; bi = e; }
    }
    used |= 1u << bi; lv[k] = best; si[k] = bi;
  }
  if (lane == 0) {
    float m = lv[0], s = 0.f, w[4];
#pragma unroll
    for (int k = 0; k < 4; ++k) { w[k] = __expf(lv[k] - m); s += w[k]; }
    float inv = 1.f / s;
#pragma unroll
    for (int k = 0; k < 4; ++k) { topw[tok * 4 + k] = w[k] * inv; topi[tok * 4 + k] = si[k]; }
  }
}

// ---------- tiny bookkeeping kernels ----------
__global__ void zero_kernel(int* b) { if (threadIdx.x < 64) b[threadIdx.x] = 0; }

__global__ void count_kernel(const int* __restrict__ topi, int* counts, int n) {
  int i = blockIdx.x * 256 + threadIdx.x;
  if (i < n) atomicAdd(&counts[topi[i]], 1);
}

__global__ void offsets_kernel(const int* counts, int* eoff) {
  if (threadIdx.x == 0 && blockIdx.x == 0) {
    int o = 0;
    for (int e = 0; e < NEXP; ++e) { eoff[e] = o; o += (counts[e] + 127) & ~127; }
    eoff[NEXP] = o;
  }
}

__global__ void prefill_kernel(int* gtok, float* gwt, int cap) {
  int i = blockIdx.x * 256 + threadIdx.x;
  if (i < cap) { gtok[i] = 0; gwt[i] = 0.f; }
}

__global__ void scatter_kernel(const int* __restrict__ topi, const float* __restrict__ topw,
                               const int* __restrict__ eoff, int* cursors,
                               int* gtok, float* gwt, int* posmap, int n) {
  int i = blockIdx.x * 256 + threadIdx.x;
  if (i >= n) return;
  int e = topi[i];
  int pos = eoff[e] + atomicAdd(&cursors[e], 1);
  gtok[pos] = i >> 2;
  gwt[pos] = topw[i] * 0.8f;   // fold k/(k+1)
  posmap[i] = pos;
}

// ---------- final combine: out = 0.2*shared (already in out) + sum_k ecout[pos[t][k]] ----------
__global__ __launch_bounds__(256) void combine_kernel(const unsigned short* __restrict__ ecout,
                                                      const int* __restrict__ posmap,
                                                      float* __restrict__ out, int n8) {
  int i = blockIdx.x * 256 + threadIdx.x;   // one thread per 8 d-elems
  if (i >= n8) return;
  int t = i >> 8;                            // DDIM/8 = 256 chunks per token
  int c = i & 255;
  int4 pv = *(const int4*)&posmap[t * 4];
  float s[8];
  float4 o0 = ((const float4*)out)[(size_t)i * 2];
  float4 o1 = ((const float4*)out)[(size_t)i * 2 + 1];
  s[0]=o0.x; s[1]=o0.y; s[2]=o0.z; s[3]=o0.w; s[4]=o1.x; s[5]=o1.y; s[6]=o1.z; s[7]=o1.w;
  int pos[4] = {pv.x, pv.y, pv.z, pv.w};
#pragma unroll
  for (int k = 0; k < 4; ++k) {
    uint4 v = ((const uint4*)(ecout + (size_t)pos[k] * DDIM))[c];
    unsigned* pw = (unsigned*)&v;
#pragma unroll
    for (int w = 0; w < 4; ++w) {
      s[w * 2]     += b2f((unsigned short)(pw[w] & 0xffffu));
      s[w * 2 + 1] += b2f((unsigned short)(pw[w] >> 16));
    }
  }
  float4 r0 = {s[0], s[1], s[2], s[3]}, r1 = {s[4], s[5], s[6], s[7]};
  ((float4*)out)[(size_t)i * 2] = r0;
  ((float4*)out)[(size_t)i * 2 + 1] = r1;
}

// =====================================================================
// Dual-B SwiGLU GEMM: G[M,N] = silu(A@W1^T) * (A@W3^T) * scale, 128x128 tile,
// BK=64, 512 thr / 8 waves (wave tile 64x32). W1,W3 are [N][K] bf16.
// MODE 0: direct A rows, single weight pair, scale=1 — R4-proven m-fastest map
// MODE 2: A rows gathered via gtok[], per-expert weights, scale=gwt[row] — tile_map
// =====================================================================
template <int MODE>
__global__ __launch_bounds__(512) void gemm_dual(const unsigned short* __restrict__ A,
                                                 const unsigned short* __restrict__ W1,
                                                 const unsigned short* __restrict__ W3,
                                                 unsigned short* __restrict__ G,
                                                 int N, int K, int MB,
                                                 const int* __restrict__ gtok,
                                                 const float* __restrict__ gwt,
                                                 const int* __restrict__ eoff) {
  __shared__ unsigned short sA[128 * 64];
  __shared__ unsigned short s1[128 * 64];
  __shared__ unsigned short s3[128 * 64];
  __shared__ int sIdx[128];

  int nwg = gridDim.x;
  int wg = xcd_swz(blockIdx.x, nwg);
  int m0, n0;
  if constexpr (MODE == 0) {
    // R4-proven simple mapping (shared dual measured 157 us / 916 TF with this)
    m0 = (wg % MB) * 128;
    n0 = (wg / MB) * 128;
  } else {
    int mb, nb;
    tile_map(wg, MB, nwg / MB, mb, nb);
    m0 = mb * 128;
    n0 = nb * 128;
  }

  const unsigned short* W1e = W1;
  const unsigned short* W3e = W3;
  if constexpr (MODE == 2) {
    if (m0 >= eoff[NEXP]) return;              // block-uniform
    int e = 0;
    while (m0 >= eoff[e + 1]) ++e;
    size_t wofs = (size_t)e * N * K;
    W1e += wofs; W3e += wofs;
  }

  int tid = threadIdx.x, lane = tid & 63, wv = tid >> 6;
  if constexpr (MODE == 2) {
    if (tid < 128) sIdx[tid] = gtok[m0 + tid];
    __syncthreads();
  }

  int wm = wv >> 2, wn = wv & 3;             // wave tile: rows wm*64+, cols wn*32+
  f32x4 ac1[4][2], ac3[4][2];
#pragma unroll
  for (int mi = 0; mi < 4; ++mi)
#pragma unroll
    for (int ni = 0; ni < 2; ++ni) { ac1[mi][ni] = (f32x4){0,0,0,0}; ac3[mi][ni] = (f32x4){0,0,0,0}; }

  for (int kt = 0; kt < K; kt += 64) {
    // stage A, W1, W3 tiles: [128 rows][64 k] bf16, XOR-swizzled via pre-swizzled source
#pragma unroll
    for (int c = 0; c < 2; ++c) {
      int bofs = (wv * 2 + c) * 1024 + lane * 16;          // byte offset within tile
      int row = bofs >> 7;                                 // 128 B per row
      int sch = ((bofs >> 4) & 7) ^ (row & 7);             // source chunk (inverse swizzle)
      int ar;
      if constexpr (MODE == 2) ar = sIdx[row]; else ar = m0 + row;
      gload16(A   + (size_t)ar * K        + kt + sch * 8, &sA[(wv * 2 + c) * 512]);
      gload16(W1e + (size_t)(n0 + row) * K + kt + sch * 8, &s1[(wv * 2 + c) * 512]);
      gload16(W3e + (size_t)(n0 + row) * K + kt + sch * 8, &s3[(wv * 2 + c) * 512]);
    }
    __syncthreads();
#pragma unroll
    for (int kk = 0; kk < 2; ++kk) {
      bf16x8 af[4], b1[2], b3[2];
#pragma unroll
      for (int mi = 0; mi < 4; ++mi) {
        int row = wm * 64 + mi * 16 + (lane & 15);
        int ch = (kk * 4 + (lane >> 4)) ^ (row & 7);
        af[mi] = *(const bf16x8*)&sA[row * 64 + ch * 8];
      }
#pragma unroll
      for (int ni = 0; ni < 2; ++ni) {
        int row = wn * 32 + ni * 16 + (lane & 15);
        int ch = (kk * 4 + (lane >> 4)) ^ (row & 7);
        b1[ni] = *(const bf16x8*)&s1[row * 64 + ch * 8];
        b3[ni] = *(const bf16x8*)&s3[row * 64 + ch * 8];
      }
#pragma unroll
      for (int mi = 0; mi < 4; ++mi)
#pragma unroll
        for (int ni = 0; ni < 2; ++ni) {
          ac1[mi][ni] = __builtin_amdgcn_mfma_f32_16x16x32_bf16(af[mi], b1[ni], ac1[mi][ni], 0, 0, 0);
          ac3[mi][ni] = __builtin_amdgcn_mfma_f32_16x16x32_bf16(af[mi], b3[ni], ac3[mi][ni], 0, 0, 0);
        }
    }
    __syncthreads();
  }

  // epilogue: g = silu(c1)*c3*scale ; C/D layout col=lane&15, row=(lane>>4)*4+j
#pragma unroll
  for (int mi = 0; mi < 4; ++mi)
#pragma unroll
    for (int ni = 0; ni < 2; ++ni) {
      int cc = n0 + wn * 32 + ni * 16 + (lane & 15);
#pragma unroll
      for (int j = 0; j < 4; ++j) {
        int rr = m0 + wm * 64 + mi * 16 + ((lane >> 4) << 2) + j;
        float sc;
        if constexpr (MODE == 2) sc = gwt[rr]; else sc = 1.f;
        float g = silu_f(ac1[mi][ni][j]) * ac3[mi][ni][j] * sc;
        G[(size_t)rr * N + cc] = f2b(g);
      }
    }
}

// ---------- single-B bf16 GEMM: 128x256 tile, BK=64, 512 thr / 8 waves ----------
// wave tile 64x64; MODE 1: direct A, Cf = v*scale (fp32)
// MODE 4: direct A (gathered space), per-expert Bt segment, C->bf16
template <int MODE>
__global__ __launch_bounds__(512) void gemm_bt8(const unsigned short* __restrict__ A,
                                                const unsigned short* __restrict__ Bt,
                                                unsigned short* __restrict__ Cbf,
                                                float* __restrict__ Cf,
                                                int N, int K, int MB,
                                                const int* __restrict__ eoff,
                                                float scale) {
  __shared__ unsigned short sA[128 * 64];   // 16 KB
  __shared__ unsigned short sB[256 * 64];   // 32 KB

  int nwg = gridDim.x;
  int wg = xcd_swz(blockIdx.x, nwg);
  int mb, nb;
  tile_map(wg, MB, nwg / MB, mb, nb);
  int m0 = mb * 128;
  int n0 = nb * 256;

  const unsigned short* Bte = Bt;
  if constexpr (MODE == 4) {
    if (m0 >= eoff[NEXP]) return;
    int e = 0;
    while (m0 >= eoff[e + 1]) ++e;
    Bte = Bt + (size_t)e * N * K;
  }
  int tid = threadIdx.x, lane = tid & 63, wv = tid >> 6;
  int wm = wv >> 2, wn = wv & 3;            // wave tile: rows wm*64+, cols wn*64+
  f32x4 acc[4][4];
#pragma unroll
  for (int mi = 0; mi < 4; ++mi)
#pragma unroll
    for (int ni = 0; ni < 4; ++ni) acc[mi][ni] = (f32x4){0.f, 0.f, 0.f, 0.f};

  for (int kt = 0; kt < K; kt += 64) {
#pragma unroll
    for (int c = 0; c < 2; ++c) {           // stage A (16 KB)
      int bofs = (wv * 2 + c) * 1024 + lane * 16;
      int row = bofs >> 7;
      int sch = ((bofs >> 4) & 7) ^ (row & 7);
      gload16(A + (size_t)(m0 + row) * K + kt + sch * 8, &sA[(wv * 2 + c) * 512]);
    }
#pragma unroll
    for (int c = 0; c < 4; ++c) {           // stage B (32 KB, 256 rows)
      int bofs = (wv * 4 + c) * 1024 + lane * 16;
      int row = bofs >> 7;
      int sch = ((bofs >> 4) & 7) ^ (row & 7);
      gload16(Bte + (size_t)(n0 + row) * K + kt + sch * 8, &sB[(wv * 4 + c) * 512]);
    }
    __syncthreads();
#pragma unroll
    for (int kk = 0; kk < 2; ++kk) {
      bf16x8 af[4], bfv[4];
#pragma unroll
      for (int mi = 0; mi < 4; ++mi) {
        int row = wm * 64 + mi * 16 + (lane & 15);
        int ch = (kk * 4 + (lane >> 4)) ^ (row & 7);
        af[mi] = *(const bf16x8*)&sA[row * 64 + ch * 8];
      }
#pragma unroll
      for (int ni = 0; ni < 4; ++ni) {
        int row = wn * 64 + ni * 16 + (lane & 15);
        int ch = (kk * 4 + (lane >> 4)) ^ (row & 7);
        bfv[ni] = *(const bf16x8*)&sB[row * 64 + ch * 8];
      }
#pragma unroll
      for (int mi = 0; mi < 4; ++mi)
#pragma unroll
        for (int ni = 0; ni < 4; ++ni)
          acc[mi][ni] = __builtin_amdgcn_mfma_f32_16x16x32_bf16(af[mi], bfv[ni], acc[mi][ni], 0, 0, 0);
    }
    __syncthreads();
  }

#pragma unroll
  for (int mi = 0; mi < 4; ++mi)
#pragma unroll
    for (int ni = 0; ni < 4; ++ni) {
      int cc = n0 + wn * 64 + ni * 16 + (lane & 15);
#pragma unroll
      for (int j = 0; j < 4; ++j) {
        int rr = m0 + wm * 64 + mi * 16 + ((lane >> 4) << 2) + j;
        float v = acc[mi][ni][j];
        if constexpr (MODE == 1) Cf[(size_t)rr * N + cc] = v * scale;
        else Cbf[(size_t)rr * N + cc] = f2b(v);
      }
    }
}

extern "C" void kernel_launch(void* const* d_in, const int* in_sizes, int n_in,
                              void* d_out, int out_size, void* d_ws, size_t ws_size,
                              hipStream_t stream) {
  const float* x   = (const float*)d_in[0];
  const float* wr  = (const float*)d_in[1];
  const float* we1 = (const float*)d_in[2];
  const float* we3 = (const float*)d_in[3];
  const float* we2 = (const float*)d_in[4];
  const float* ws1 = (const float*)d_in[5];
  const float* ws3 = (const float*)d_in[6];
  const float* ws2 = (const float*)d_in[7];
  float* out = (float*)d_out;   // fp32 output per reference dtype

  char* p = (char*)d_ws;
  auto take = [&](size_t bytes) { char* r = p; p += (bytes + 255) & ~(size_t)255; return r; };
  unsigned short* xbf   = (unsigned short*)take((size_t)TTOK * DDIM * 2);    // 16 MiB
  unsigned short* ehg   = (unsigned short*)take((size_t)CAPR * HDIM * 2);    // 36 MiB (expert g)
  unsigned short* gsh   = (unsigned short*)take((size_t)TTOK * HSDIM * 2);   // 32 MiB (shared g)
  unsigned short* ecout = (unsigned short*)take((size_t)CAPR * DDIM * 2);    // 72 MiB
  unsigned short* twArena = (unsigned short*)take((size_t)NEXP * HDIM * DDIM * 2);  // 64 MiB
  float* topw = (float*)take((size_t)TTOK * 4 * 4);
  int*   topi = (int*)take((size_t)TTOK * 4 * 4);
  int*   gtok = (int*)take((size_t)CAPR * 4);
  float* gwt  = (float*)take((size_t)CAPR * 4);
  int*   posmap = (int*)take((size_t)TTOK * 4 * 4);
  int*   ibuf = (int*)take(256);   // [0:16) counts, [16:32) cursors, [32:49) eoff
  if ((size_t)(p - (char*)d_ws) > ws_size) return;  // ws too small -> visible failure

  unsigned short* twA = twArena;                                   // first 32 MiB
  unsigned short* twB = twArena + (size_t)8 * DDIM * HDIM;         // second 32 MiB
  // we3^T (64 MiB) aliases gsh(32) + first 32 MiB of ecout — both dead in expert GEMM1 phase;
  // ecout's overlap region is rewritten only by gemm_bt8<4> afterwards.
  unsigned short* we3t = gsh;

  int* counts  = ibuf;
  int* cursors = ibuf + 16;
  int* eoff    = ibuf + 32;

  // ---- prep: router (emits xbf too); permutation ----
  router_kernel<<<TTOK / 4, 256, 0, stream>>>(x, wr, topw, topi, xbf);
  zero_kernel<<<1, 64, 0, stream>>>(ibuf);
  count_kernel<<<TTOK * 4 / 256, 256, 0, stream>>>(topi, counts, TTOK * 4);
  offsets_kernel<<<1, 64, 0, stream>>>(counts, eoff);
  prefill_kernel<<<CAPR / 256, 256, 0, stream>>>(gtok, gwt, CAPR);
  scatter_kernel<<<TTOK * 4 / 256, 256, 0, stream>>>(topi, topw, eoff, cursors, gtok, gwt, posmap, TTOK * 4);

  // ---- shared MLP: gsh = silu(x@ws1)*(x@ws3); out = 0.2 * gsh @ ws2 ----
  transpose_f2b2<<<dim3(HSDIM / 64, DDIM / 64, 2), 256, 0, stream>>>(ws1, ws3, twA, twB, DDIM, HSDIM, 1);
  gemm_dual<0><<<(TTOK / 128) * (HSDIM / 128), 512, 0, stream>>>(xbf, twA, twB, gsh, HSDIM, DDIM,
                                                                 TTOK / 128, nullptr, nullptr, nullptr);
  transpose_f2b2<<<dim3(DDIM / 64, HSDIM / 64, 1), 256, 0, stream>>>(ws2, ws2, twA, twA, HSDIM, DDIM, 1);
  gemm_bt8<1><<<(TTOK / 128) * (DDIM / 256), 512, 0, stream>>>(gsh, twA, nullptr, out, DDIM, HSDIM,
                                                               TTOK / 128, nullptr, 0.2f);

  // ---- experts (single merged launch over all 16): ehg = silu(xg@we1)*(xg@we3)*gwt ----
  transpose_f2b2<<<dim3(HDIM / 64, DDIM / 64, 2 * NEXP), 256, 0, stream>>>(we1, we3, twArena, we3t,
                                                                           DDIM, HDIM, NEXP);
  gemm_dual<2><<<(CAPR / 128) * (HDIM / 128), 512, 0, stream>>>(xbf, twArena, we3t, ehg, HDIM, DDIM,
                                                                CAPR / 128, gtok, gwt, eoff);
  // expert GEMM2: ecout = ehg @ we2 (per-expert), bf16 at gathered rows
  transpose_f2b2<<<dim3(DDIM / 64, HDIM / 64, NEXP), 256, 0, stream>>>(we2, we2, twArena, twArena,
                                                                       HDIM, DDIM, NEXP);
  gemm_bt8<4><<<(CAPR / 128) * (DDIM / 256), 512, 0, stream>>>(ehg, twArena, ecout, nullptr, DDIM, HDIM,
                                                               CAPR / 128, eoff, 0.f);

  // ---- out = 0.2*shared + sum_k ecout[pos[t][k]] ----
  combine_kernel<<<TTOK * DDIM / 8 / 256, 256, 0, stream>>>(ecout, posmap, out, TTOK * DDIM / 8);
}